// Round 1
// 869.091 us; speedup vs baseline: 1.5791x; 1.5791x over previous
//
#include <hip/hip_runtime.h>

// Problem constants
#define B_   16
#define C_   96
#define H_   128
#define W_   128
#define HW_  16384
#define CPG_ 24
#define NPG_ 393216.0f
#define TDIM_ 256
#define PLANE_ ((size_t)B_ * C_ * HW_)   // 25165824

typedef unsigned short ushort_t;
typedef __bf16 bf16x8 __attribute__((ext_vector_type(8)));
typedef float  f32x4  __attribute__((ext_vector_type(4)));
typedef unsigned short u16x8 __attribute__((ext_vector_type(8)));

#define ICP 104   // padded K-stride in LDS (bf16 elems), 16B-aligned rows

__device__ __forceinline__ float silu_f(float x) { return x / (1.f + __expf(-x)); }
__device__ __forceinline__ float bf2f(ushort_t u) {
    union { float f; unsigned int i; } x; x.i = ((unsigned int)u) << 16; return x.f;
}
__device__ __forceinline__ ushort_t f2bf(float f) {
    __bf16 h = (__bf16)f; return *(ushort_t*)&h;
}

// ---------------------------------------------------------------------------
// t = silu(t_emb @ wt.T + bt) -> tvec[B][192]
// ---------------------------------------------------------------------------
__global__ void temb_kernel(const float* __restrict__ t_emb,
                            const float* __restrict__ wt,
                            const float* __restrict__ bt,
                            float* __restrict__ tvec) {
    int idx = blockIdx.x * 256 + threadIdx.x;
    if (idx >= B_ * 192) return;
    int b = idx / 192, o = idx - b * 192;
    float a = bt[o];
    const float* te = t_emb + b * TDIM_;
    const float* wr = wt + o * TDIM_;
    for (int k = 0; k < TDIM_; ++k) a += te[k] * wr[k];
    tvec[idx] = silu_f(a);
}

// ---------------------------------------------------------------------------
// fp32 -> bf16 cast
// ---------------------------------------------------------------------------
__global__ void castbf_kernel(const float* __restrict__ src,
                              ushort_t* __restrict__ dst, int n4) {
    int i = blockIdx.x * 256 + threadIdx.x;
    if (i >= n4) return;
    float4 v = ((const float4*)src)[i];
    ushort4 u = { f2bf(v.x), f2bf(v.y), f2bf(v.z), f2bf(v.w) };
    ((ushort4*)dst)[i] = u;
}

// ---------------------------------------------------------------------------
// Pre-cast conv weights fp32 [oc][ic][3][3] -> bf16 [kk][oc][ic].
// Run once; makes per-kk LDS weight staging a pure aligned 16B bf16 copy.
// grid 324 x 256 = 82944 exactly.
// ---------------------------------------------------------------------------
__global__ void castw_kernel(const float* __restrict__ w1,
                             const float* __restrict__ w2,
                             ushort_t* __restrict__ wbf1,
                             ushort_t* __restrict__ wbf2) {
    int i = blockIdx.x * 256 + threadIdx.x;
    int ic = i % 96;
    int t  = i / 96;
    int oc = t % 96;
    int kk = t / 96;
    int src = (oc * 96 + ic) * 9 + kk;
    wbf1[i] = f2bf(w1[src]);
    wbf2[i] = f2bf(w2[src]);
}

// ---------------------------------------------------------------------------
// conv3x3 implicit-GEMM MFMA + bias + GN stats.
// Staging rework vs previous version:
//  - input: ushort8 (16B) coalesced global loads; tasks ordered so consecutive
//    lanes hold consecutive ic -> each transposed ds_write_b16 instruction
//    covers 128B contiguous = bank-conflict-free (old path: 2B scalar loads +
//    8-way-conflicted writes, 99 iters of div/mod address math).
//  - weights: pre-cast bf16 [kk][oc][ic]; per-kk stage is 4.5 aligned 16B
//    copies, and the NEXT kk's weights are prefetched into registers before
//    the MFMA loop so L2 latency hides under compute (async-stage split).
// MFMA math / fragment layout / epilogue identical to the verified version.
// ---------------------------------------------------------------------------
__global__ __launch_bounds__(256, 2)
void conv3x3_mfma_kernel(const ushort_t* __restrict__ xbf,
                         const ushort_t* __restrict__ wbf,   // [9][96][96] bf16
                         const float* __restrict__ bias,
                         float* __restrict__ out,
                         float* __restrict__ stats) {
    __shared__ __align__(16) ushort_t ti[4 * 66 * ICP];
    __shared__ __align__(16) ushort_t wc[96 * ICP];
    __shared__ float red[4][96][2];

    const int b   = blockIdx.z;
    const int y0  = blockIdx.y * 2;
    const int x0  = blockIdx.x * 64;
    const int tid = threadIdx.x;
    const int wv   = tid >> 6;
    const int lane = tid & 63;
    const int l15  = lane & 15;
    const int quad = lane >> 4;

    // ---- interior input staging: tasks (r,xc,ic) = 4*8*96 = 3072, 12 iters
#pragma unroll
    for (int it = 0; it < 12; ++it) {
        int idx = it * 256 + tid;
        int ic = idx % 96;           // consecutive lanes -> consecutive ic
        int t2 = idx / 96;
        int xc = t2 & 7;
        int r  = t2 >> 3;
        int gy = y0 - 1 + r;
        u16x8 v = {};
        if (gy >= 0 && gy < H_)
            v = *(const u16x8*)&xbf[((b * 96 + ic) * H_ + gy) * W_ + x0 + xc * 8];
        ushort_t* dst = &ti[(r * 66 + xc * 8 + 1) * ICP + ic];
#pragma unroll
        for (int j = 0; j < 8; ++j) dst[j * ICP] = v[j];
    }
    // ---- halo columns xi=0 (gx=x0-1) and xi=65 (gx=x0+64): 768 scalar elems
    {
        int idx = tid;
#pragma unroll
        for (int it = 0; it < 3; ++it, idx += 256) {
            int ic = idx % 96;
            int t2 = idx / 96;       // 0..7
            int r = t2 >> 1, side = t2 & 1;
            int xi = side ? 65 : 0;
            int gx = x0 - 1 + xi;
            int gy = y0 - 1 + r;
            ushort_t vv = 0;
            if (gy >= 0 && gy < H_ && gx >= 0 && gx < W_)
                vv = xbf[((b * 96 + ic) * H_ + gy) * W_ + gx];
            ti[(r * 66 + xi) * ICP + ic] = vv;
        }
    }

    // ---- per-thread weight-staging task table (loop-invariant offsets)
    //      tasks (oc, icb) = 96*12 = 1152; threads < 128 own a 5th task.
    int wsrc[5], wdst[5];
#pragma unroll
    for (int i = 0; i < 5; ++i) {
        int idx = tid + i * 256;
        int icb = idx % 12;
        int oc  = idx / 12;
        wsrc[i] = oc * 96 + icb * 8;
        wdst[i] = oc * ICP + icb * 8;
    }
    u16x8 wreg[5];
#pragma unroll
    for (int i = 0; i < 4; ++i) wreg[i] = *(const u16x8*)&wbf[wsrc[i]];
    if (tid < 128) wreg[4] = *(const u16x8*)&wbf[wsrc[4]];

    f32x4 acc[2][6];
#pragma unroll
    for (int m = 0; m < 2; ++m)
#pragma unroll
        for (int nt = 0; nt < 6; ++nt)
            acc[m][nt] = (f32x4){0.f, 0.f, 0.f, 0.f};

    for (int kk = 0; kk < 9; ++kk) {
        const int ky = kk / 3, kx = kk - ky * 3;
        __syncthreads();   // prev compute done reading wc (covers ti at kk=0)
#pragma unroll
        for (int i = 0; i < 4; ++i) *(u16x8*)&wc[wdst[i]] = wreg[i];
        if (tid < 128) *(u16x8*)&wc[wdst[4]] = wreg[4];
        __syncthreads();
        if (kk < 8) {      // prefetch next kk's weights; completes under MFMA
            const ushort_t* wsk = wbf + (kk + 1) * 9216;
#pragma unroll
            for (int i = 0; i < 4; ++i) wreg[i] = *(const u16x8*)&wsk[wsrc[i]];
            if (tid < 128) wreg[4] = *(const u16x8*)&wsk[wsrc[4]];
        }
#pragma unroll 1
        for (int ck = 0; ck < 3; ++ck) {
            const int kbase = ck * 32 + quad * 8;
            bf16x8 a0 = *(const bf16x8*)&ti[((0 + ky) * 66 + (wv * 16 + l15 + kx)) * ICP + kbase];
            bf16x8 a1 = *(const bf16x8*)&ti[((1 + ky) * 66 + (wv * 16 + l15 + kx)) * ICP + kbase];
#pragma unroll
            for (int nt = 0; nt < 6; ++nt) {
                bf16x8 bv = *(const bf16x8*)&wc[(nt * 16 + l15) * ICP + kbase];
                acc[0][nt] = __builtin_amdgcn_mfma_f32_16x16x32_bf16(a0, bv, acc[0][nt], 0, 0, 0);
                acc[1][nt] = __builtin_amdgcn_mfma_f32_16x16x32_bf16(a1, bv, acc[1][nt], 0, 0, 0);
            }
        }
    }

    float lsum[6], lsq[6];
#pragma unroll
    for (int nt = 0; nt < 6; ++nt) { lsum[nt] = 0.f; lsq[nt] = 0.f; }

#pragma unroll
    for (int m = 0; m < 2; ++m) {
        const int gy = y0 + m;
        const int gx = x0 + wv * 16 + quad * 4;
#pragma unroll
        for (int nt = 0; nt < 6; ++nt) {
            const int oc = nt * 16 + l15;
            const float bz = bias[oc];
            float v0 = acc[m][nt][0] + bz;
            float v1 = acc[m][nt][1] + bz;
            float v2 = acc[m][nt][2] + bz;
            float v3 = acc[m][nt][3] + bz;
            float4 vv = make_float4(v0, v1, v2, v3);
            *(float4*)&out[((b * 96 + oc) * H_ + gy) * W_ + gx] = vv;
            lsum[nt] += v0 + v1 + v2 + v3;
            lsq[nt]  += v0 * v0 + v1 * v1 + v2 * v2 + v3 * v3;
        }
    }
#pragma unroll
    for (int nt = 0; nt < 6; ++nt) {
        float s = lsum[nt], q = lsq[nt];
        s += __shfl_down(s, 32, 64);
        s += __shfl_down(s, 16, 64);
        q += __shfl_down(q, 32, 64);
        q += __shfl_down(q, 16, 64);
        if (lane < 16) {
            red[wv][nt * 16 + lane][0] = s;
            red[wv][nt * 16 + lane][1] = q;
        }
    }
    __syncthreads();
    if (tid < 8) {
        const int g = tid >> 1, which = tid & 1;
        float v = 0.f;
        for (int oc = g * CPG_; oc < g * CPG_ + CPG_; ++oc)
            for (int w2 = 0; w2 < 4; ++w2) v += red[w2][oc][which];
        atomicAdd(&stats[(b * 4 + g) * 2 + which], v);
    }
}

// ---------------------------------------------------------------------------
// h = silu(GN(y)) * (1+shift) + bias  (IN-PLACE on d_out), emits stats2
// ---------------------------------------------------------------------------
__global__ void apply1_kernel(const float* y,
                              const float* __restrict__ stats1,
                              const float* __restrict__ g1,
                              const float* __restrict__ be1,
                              const float* __restrict__ tvec,
                              float* h,
                              float* __restrict__ stats2) {
    const int bc = blockIdx.x;
    const int b = bc / C_, c = bc - b * C_;
    const int g = c / CPG_;
    const float sum = stats1[(b * 4 + g) * 2], sumsq = stats1[(b * 4 + g) * 2 + 1];
    const float mean = sum / NPG_;
    const float var  = sumsq / NPG_ - mean * mean;
    const float rstd = rsqrtf(var + 1e-5f);
    const float sc = rstd * g1[c];
    const float sh = be1[c] - mean * sc;
    const float tsc = 1.f + tvec[b * 192 + c];
    const float tbi = tvec[b * 192 + 96 + c];

    const float4* yp = (const float4*)(y + (size_t)bc * HW_);
    float4* hp = (float4*)(h + (size_t)bc * HW_);
    float ls = 0.f, lss = 0.f;
    for (int i = threadIdx.x; i < HW_ / 4; i += 256) {
        float4 v = yp[i];
        float r0 = silu_f(v.x * sc + sh) * tsc + tbi;
        float r1 = silu_f(v.y * sc + sh) * tsc + tbi;
        float r2 = silu_f(v.z * sc + sh) * tsc + tbi;
        float r3 = silu_f(v.w * sc + sh) * tsc + tbi;
        hp[i] = make_float4(r0, r1, r2, r3);
        ls  += r0 + r1 + r2 + r3;
        lss += r0*r0 + r1*r1 + r2*r2 + r3*r3;
    }
    for (int off = 32; off > 0; off >>= 1) {
        ls  += __shfl_down(ls, off, 64);
        lss += __shfl_down(lss, off, 64);
    }
    if ((threadIdx.x & 63) == 0) {
        atomicAdd(&stats2[(b * 4 + g) * 2 + 0], ls);
        atomicAdd(&stats2[(b * 4 + g) * 2 + 1], lss);
    }
}

// ---------------------------------------------------------------------------
// GN apply -> bf16 output (qkv GEMM input)
// ---------------------------------------------------------------------------
__global__ void gn_bf16_kernel(const float* __restrict__ in,
                               const float* __restrict__ stats,
                               const float* __restrict__ gamma,
                               const float* __restrict__ beta,
                               ushort_t* __restrict__ outb) {
    const int bc = blockIdx.x;
    const int b = bc / C_, c = bc - b * C_;
    const int g = c / CPG_;
    const float sum = stats[(b * 4 + g) * 2], sumsq = stats[(b * 4 + g) * 2 + 1];
    const float mean = sum / NPG_;
    const float var  = sumsq / NPG_ - mean * mean;
    const float rstd = rsqrtf(var + 1e-5f);
    const float sc = rstd * gamma[c];
    const float sh = beta[c] - mean * sc;
    const float4* ip = (const float4*)(in + (size_t)bc * HW_);
    ushort4* op = (ushort4*)(outb + (size_t)bc * HW_);
    for (int i = threadIdx.x; i < HW_ / 4; i += 256) {
        float4 v = ip[i];
        ushort4 u = { f2bf(v.x * sc + sh), f2bf(v.y * sc + sh),
                      f2bf(v.z * sc + sh), f2bf(v.w * sc + sh) };
        op[i] = u;
    }
}

// ---------------------------------------------------------------------------
// GN apply fp32 (+silu), in-place capable
// ---------------------------------------------------------------------------
__global__ void gn_apply_kernel(const float* in,
                                const float* __restrict__ stats,
                                const float* __restrict__ gamma,
                                const float* __restrict__ beta,
                                float* out, int dosilu) {
    const int bc = blockIdx.x;
    const int b = bc / C_, c = bc - b * C_;
    const int g = c / CPG_;
    const float sum = stats[(b * 4 + g) * 2], sumsq = stats[(b * 4 + g) * 2 + 1];
    const float mean = sum / NPG_;
    const float var  = sumsq / NPG_ - mean * mean;
    const float rstd = rsqrtf(var + 1e-5f);
    const float sc = rstd * gamma[c];
    const float sh = beta[c] - mean * sc;
    const float4* ip = (const float4*)(in + (size_t)bc * HW_);
    float4* op = (float4*)(out + (size_t)bc * HW_);
    for (int i = threadIdx.x; i < HW_ / 4; i += 256) {
        float4 v = ip[i];
        float r0 = v.x * sc + sh, r1 = v.y * sc + sh;
        float r2 = v.z * sc + sh, r3 = v.w * sc + sh;
        if (dosilu) { r0 = silu_f(r0); r1 = silu_f(r1); r2 = silu_f(r2); r3 = silu_f(r3); }
        op[i] = make_float4(r0, r1, r2, r3);
    }
}

// ---------------------------------------------------------------------------
// qkv 1x1 GEMM: out plane ocg = s*96+oc, bf16. grid (2, 64, 48): z = b*3+s
// Staging vectorized: 16B input loads + conflict-free transposed b16 writes;
// weights as float4 loads + b64 writes (9 iters vs 36 scalar).
// ---------------------------------------------------------------------------
__global__ __launch_bounds__(256, 3)
void qkv_gemm_kernel(const ushort_t* __restrict__ xq,
                     const float* __restrict__ qw,   // [288][96]
                     const float* __restrict__ qb,
                     ushort_t* __restrict__ qkvbuf) {
    __shared__ __align__(16) ushort_t ti[2 * 64 * ICP];
    __shared__ __align__(16) ushort_t wc[96 * ICP];

    const int bz = blockIdx.z;
    const int b = bz / 3, s = bz - b * 3;
    const int y0 = blockIdx.y * 2;
    const int x0 = blockIdx.x * 64;
    const int tid = threadIdx.x;
    const int wv = tid >> 6, lane = tid & 63;
    const int l15 = lane & 15, quad = lane >> 4;

    // input: tasks (r,xc,ic) = 2*8*96 = 1536, 6 iters
#pragma unroll
    for (int it = 0; it < 6; ++it) {
        int idx = it * 256 + tid;
        int ic = idx % 96;
        int t2 = idx / 96;
        int xc = t2 & 7;
        int r  = t2 >> 3;
        u16x8 v = *(const u16x8*)&xq[((b * 96 + ic) * H_ + y0 + r) * W_ + x0 + xc * 8];
        ushort_t* dst = &ti[(r * 64 + xc * 8) * ICP + ic];
#pragma unroll
        for (int j = 0; j < 8; ++j) dst[j * ICP] = v[j];
    }
    // weights: tasks (oc,icq) = 96*24 = 2304, 9 iters
#pragma unroll
    for (int it = 0; it < 9; ++it) {
        int idx = it * 256 + tid;
        int icq = idx % 24;
        int oc  = idx / 24;
        float4 wv4 = *(const float4*)&qw[(s * 96 + oc) * 96 + icq * 4];
        ushort4 u = { f2bf(wv4.x), f2bf(wv4.y), f2bf(wv4.z), f2bf(wv4.w) };
        *(ushort4*)&wc[oc * ICP + icq * 4] = u;
    }
    __syncthreads();

    f32x4 acc[2][6];
#pragma unroll
    for (int m = 0; m < 2; ++m)
#pragma unroll
        for (int nt = 0; nt < 6; ++nt) acc[m][nt] = (f32x4){0.f, 0.f, 0.f, 0.f};

#pragma unroll
    for (int ck = 0; ck < 3; ++ck) {
        const int kbase = ck * 32 + quad * 8;
        bf16x8 a0 = *(const bf16x8*)&ti[(0 * 64 + wv * 16 + l15) * ICP + kbase];
        bf16x8 a1 = *(const bf16x8*)&ti[(1 * 64 + wv * 16 + l15) * ICP + kbase];
#pragma unroll
        for (int nt = 0; nt < 6; ++nt) {
            bf16x8 bv = *(const bf16x8*)&wc[(nt * 16 + l15) * ICP + kbase];
            acc[0][nt] = __builtin_amdgcn_mfma_f32_16x16x32_bf16(a0, bv, acc[0][nt], 0, 0, 0);
            acc[1][nt] = __builtin_amdgcn_mfma_f32_16x16x32_bf16(a1, bv, acc[1][nt], 0, 0, 0);
        }
    }

#pragma unroll
    for (int m = 0; m < 2; ++m) {
        const int gy = y0 + m;
        const int gx = x0 + wv * 16 + quad * 4;
#pragma unroll
        for (int nt = 0; nt < 6; ++nt) {
            const int ocg = s * 96 + nt * 16 + l15;
            const float bz2 = qb[ocg];
            ushort4 u = { f2bf(acc[m][nt][0] + bz2), f2bf(acc[m][nt][1] + bz2),
                          f2bf(acc[m][nt][2] + bz2), f2bf(acc[m][nt][3] + bz2) };
            *(ushort4*)&qkvbuf[((size_t)(b * 288 + ocg) * H_ + gy) * W_ + gx] = u;
        }
    }
}

// ---------------------------------------------------------------------------
// Attention v2 (unchanged; verified)
// ---------------------------------------------------------------------------
#define QKS 1032   // qk/ost channel stride (bf16 elems)
__global__ __launch_bounds__(256, 2)
void attn2_kernel(const ushort_t* __restrict__ qkv,
                  ushort_t* __restrict__ obuf, int shift, int accumulate) {
    __shared__ __align__(16) ushort_t qk[12 * QKS];        // Q d=0..5, K d=6..11
    __shared__ __align__(16) ushort_t vt[16 * 512 + 32];   // [wx][px][8] slots, zero-padded
    __shared__ __align__(16) ushort_t ost[6 * QKS];        // O staging [d][r][128]

    const int h = blockIdx.x, wy = blockIdx.y, b = blockIdx.z;
    const int tid = threadIdx.x;
    const int wv = tid >> 6, lane = tid & 63;
    const int l15 = lane & 15, quad = lane >> 4;

    for (int i = tid; i < (16 * 512 + 32) / 2; i += 256) ((unsigned int*)vt)[i] = 0u;
    __syncthreads();

    for (int idx = tid; idx < 2304; idx += 256) {
        int xc = idx & 15;
        int t2 = idx >> 4;
        int r  = t2 & 7;
        int ch = t2 >> 3;                 // 0..17
        int part = ch / 6, d = ch - part * 6;
        int gch = part * 96 + h * 6 + d;  // q / k / v plane
        int gy = (wy * 8 + r + shift) & 127;
        size_t rowb = ((size_t)(b * 288 + gch) * H_ + gy) * W_;
        ushort4 u0, u1;
        if (shift == 0) {
            u0 = *(const ushort4*)&qkv[rowb + xc * 8];
            u1 = *(const ushort4*)&qkv[rowb + xc * 8 + 4];
        } else {
            u0 = *(const ushort4*)&qkv[rowb + ((xc * 8 + 4) & 127)];
            u1 = *(const ushort4*)&qkv[rowb + ((xc * 8 + 8) & 127)];
        }
        if (part < 2) {
            ushort_t* dst = &qk[(part * 6 + d) * QKS + r * 128 + xc * 8];
            *(ushort4*)dst = u0;
            *(ushort4*)(dst + 4) = u1;
        } else {
            ushort_t uu[8] = {u0.x, u0.y, u0.z, u0.w, u1.x, u1.y, u1.z, u1.w};
            ushort_t* base = &vt[xc * 512 + (r * 8) * 8 + d];
#pragma unroll
            for (int c = 0; c < 8; ++c) base[c * 8] = uu[c];
        }
    }
    __syncthreads();

    const float scale = 0.40824829046386302f;  // 6^-0.5
    const int dcl = (l15 < 6) ? l15 : 5;
    const int chA = 6 + dcl;
    const int chB = dcl;

    for (int i = 0; i < 4; ++i) {
        const int wx = wv * 4 + i;
        f32x4 sa = (f32x4){0.f, 0.f, 0.f, 0.f};
#pragma unroll
        for (int ck = 0; ck < 2; ++ck) {
            const int r = ck * 4 + quad;
            bf16x8 af  = *(const bf16x8*)&qk[chA * QKS + r * 128 + wx * 8];
            bf16x8 bfv = *(const bf16x8*)&qk[chB * QKS + r * 128 + wx * 8];
            sa = __builtin_amdgcn_mfma_f32_16x16x32_bf16(af, bfv, sa, 0, 0, 0);
        }
        float s0 = sa[0] * scale, s1 = sa[1] * scale, s2 = sa[2] * scale, s3 = sa[3] * scale;
        float m = -3.4e38f;
        if (quad == 0) m = fmaxf(fmaxf(s0, s1), fmaxf(s2, s3));
        else if (quad == 1) m = fmaxf(s0, s1);
        m = fmaxf(m, __shfl_xor(m, 16, 64));
        m = fmaxf(m, __shfl_xor(m, 32, 64));
        float p0 = (quad <= 1) ? __expf(s0 - m) : 0.f;
        float p1 = (quad <= 1) ? __expf(s1 - m) : 0.f;
        float p2 = (quad == 0) ? __expf(s2 - m) : 0.f;
        float p3 = (quad == 0) ? __expf(s3 - m) : 0.f;
        float sum = p0 + p1 + p2 + p3;
        sum += __shfl_xor(sum, 16, 64);
        sum += __shfl_xor(sum, 32, 64);
        float inv = 1.f / sum;
        p0 *= inv; p1 *= inv; p2 *= inv; p3 *= inv;
        float e4 = __shfl_xor(p0, 16, 64);
        float e5 = __shfl_xor(p1, 16, 64);
        bf16x8 pf;
        pf[0] = (__bf16)p0; pf[1] = (__bf16)p1; pf[2] = (__bf16)p2; pf[3] = (__bf16)p3;
        pf[4] = (__bf16)e4; pf[5] = (__bf16)e5;
        pf[6] = (__bf16)0.f; pf[7] = (__bf16)0.f;
        if (quad != 0) { bf16x8 z = {}; pf = z; }
#pragma unroll
        for (int mt = 0; mt < 4; ++mt) {
            bf16x8 av = *(const bf16x8*)&vt[wx * 512 + (mt * 16 + l15) * 8 + quad * 8];
            f32x4 o = __builtin_amdgcn_mfma_f32_16x16x32_bf16(av, pf, (f32x4){0.f,0.f,0.f,0.f}, 0, 0, 0);
            if (l15 < 6) {
                const int px = mt * 16 + quad * 4;
                const int r = px >> 3, c = px & 7;
                ushort4 st = { f2bf(o[0]), f2bf(o[1]), f2bf(o[2]), f2bf(o[3]) };
                *(ushort4*)&ost[l15 * QKS + r * 128 + wx * 8 + c] = st;
            }
        }
    }
    __syncthreads();

    for (int idx = tid; idx < 768; idx += 256) {
        int xc = idx & 15;
        int t2 = idx >> 4;
        int r = t2 & 7, d = t2 >> 3;
        int gy = (wy * 8 + r + shift) & 127;
        size_t rowb = ((size_t)(b * 96 + h * 6 + d) * H_ + gy) * W_;
        size_t a0, a1;
        if (shift == 0) { a0 = rowb + xc * 8; a1 = rowb + xc * 8 + 4; }
        else { a0 = rowb + ((xc * 8 + 4) & 127); a1 = rowb + ((xc * 8 + 8) & 127); }
        const ushort_t* src = &ost[d * QKS + r * 128 + xc * 8];
        ushort4 v0 = *(const ushort4*)src;
        ushort4 v1 = *(const ushort4*)(src + 4);
        if (accumulate) {
            ushort4 q0 = *(const ushort4*)&obuf[a0];
            ushort4 q1 = *(const ushort4*)&obuf[a1];
            v0.x = f2bf(0.5f * (bf2f(v0.x) + bf2f(q0.x)));
            v0.y = f2bf(0.5f * (bf2f(v0.y) + bf2f(q0.y)));
            v0.z = f2bf(0.5f * (bf2f(v0.z) + bf2f(q0.z)));
            v0.w = f2bf(0.5f * (bf2f(v0.w) + bf2f(q0.w)));
            v1.x = f2bf(0.5f * (bf2f(v1.x) + bf2f(q1.x)));
            v1.y = f2bf(0.5f * (bf2f(v1.y) + bf2f(q1.y)));
            v1.z = f2bf(0.5f * (bf2f(v1.z) + bf2f(q1.z)));
            v1.w = f2bf(0.5f * (bf2f(v1.w) + bf2f(q1.w)));
        }
        *(ushort4*)&obuf[a0] = v0;
        *(ushort4*)&obuf[a1] = v1;
    }
}

// ---------------------------------------------------------------------------
// proj 1x1 GEMM + residual add; emits h2 bf16 (conv2 input). grid (2,64,16)
// Same staging rework as qkv.
// ---------------------------------------------------------------------------
__global__ __launch_bounds__(256, 3)
void proj_gemm_kernel(const ushort_t* __restrict__ ob,
                      const float* __restrict__ pw,   // [96][96]
                      const float* __restrict__ pb,
                      const float* __restrict__ resid,
                      ushort_t* __restrict__ h2) {
    __shared__ __align__(16) ushort_t ti[2 * 64 * ICP];
    __shared__ __align__(16) ushort_t wc[96 * ICP];

    const int b = blockIdx.z;
    const int y0 = blockIdx.y * 2;
    const int x0 = blockIdx.x * 64;
    const int tid = threadIdx.x;
    const int wv = tid >> 6, lane = tid & 63;
    const int l15 = lane & 15, quad = lane >> 4;

#pragma unroll
    for (int it = 0; it < 6; ++it) {
        int idx = it * 256 + tid;
        int ic = idx % 96;
        int t2 = idx / 96;
        int xc = t2 & 7;
        int r  = t2 >> 3;
        u16x8 v = *(const u16x8*)&ob[((b * 96 + ic) * H_ + y0 + r) * W_ + x0 + xc * 8];
        ushort_t* dst = &ti[(r * 64 + xc * 8) * ICP + ic];
#pragma unroll
        for (int j = 0; j < 8; ++j) dst[j * ICP] = v[j];
    }
#pragma unroll
    for (int it = 0; it < 9; ++it) {
        int idx = it * 256 + tid;
        int icq = idx % 24;
        int oc  = idx / 24;
        float4 wv4 = *(const float4*)&pw[oc * 96 + icq * 4];
        ushort4 u = { f2bf(wv4.x), f2bf(wv4.y), f2bf(wv4.z), f2bf(wv4.w) };
        *(ushort4*)&wc[oc * ICP + icq * 4] = u;
    }
    __syncthreads();

    f32x4 acc[2][6];
#pragma unroll
    for (int m = 0; m < 2; ++m)
#pragma unroll
        for (int nt = 0; nt < 6; ++nt) acc[m][nt] = (f32x4){0.f, 0.f, 0.f, 0.f};

#pragma unroll
    for (int ck = 0; ck < 3; ++ck) {
        const int kbase = ck * 32 + quad * 8;
        bf16x8 a0 = *(const bf16x8*)&ti[(0 * 64 + wv * 16 + l15) * ICP + kbase];
        bf16x8 a1 = *(const bf16x8*)&ti[(1 * 64 + wv * 16 + l15) * ICP + kbase];
#pragma unroll
        for (int nt = 0; nt < 6; ++nt) {
            bf16x8 bv = *(const bf16x8*)&wc[(nt * 16 + l15) * ICP + kbase];
            acc[0][nt] = __builtin_amdgcn_mfma_f32_16x16x32_bf16(a0, bv, acc[0][nt], 0, 0, 0);
            acc[1][nt] = __builtin_amdgcn_mfma_f32_16x16x32_bf16(a1, bv, acc[1][nt], 0, 0, 0);
        }
    }

#pragma unroll
    for (int m = 0; m < 2; ++m) {
        const int gy = y0 + m;
        const int gx = x0 + wv * 16 + quad * 4;
#pragma unroll
        for (int nt = 0; nt < 6; ++nt) {
            const int oc = nt * 16 + l15;
            const float bz2 = pb[oc];
            size_t addr = ((size_t)(b * 96 + oc) * H_ + gy) * W_ + gx;
            float4 rv = *(const float4*)&resid[addr];
            ushort4 u = { f2bf(acc[m][nt][0] + bz2 + rv.x),
                          f2bf(acc[m][nt][1] + bz2 + rv.y),
                          f2bf(acc[m][nt][2] + bz2 + rv.z),
                          f2bf(acc[m][nt][3] + bz2 + rv.w) };
            *(ushort4*)&h2[addr] = u;
        }
    }
}

// ---------------------------------------------------------------------------
extern "C" void kernel_launch(void* const* d_in, const int* in_sizes, int n_in,
                              void* d_out, int out_size, void* d_ws, size_t ws_size,
                              hipStream_t stream) {
    const float* x     = (const float*)d_in[0];
    const float* t_emb = (const float*)d_in[1];
    const float* w1    = (const float*)d_in[2];
    const float* b1    = (const float*)d_in[3];
    const float* g1    = (const float*)d_in[4];
    const float* be1   = (const float*)d_in[5];
    const float* wt    = (const float*)d_in[6];
    const float* bt    = (const float*)d_in[7];
    const float* qkv_w = (const float*)d_in[8];
    const float* qkv_b = (const float*)d_in[9];
    const float* proj_w= (const float*)d_in[10];
    const float* proj_b= (const float*)d_in[11];
    const float* ga    = (const float*)d_in[12];
    const float* ba    = (const float*)d_in[13];
    const float* w2    = (const float*)d_in[14];
    const float* b2    = (const float*)d_in[15];
    const float* g2    = (const float*)d_in[16];
    const float* be2   = (const float*)d_in[17];

    float* out = (float*)d_out;

    // Workspace arena:
    // A: PLANE bf16  — xbf1 -> xq -> Obuf
    // B: 3*PLANE bf16 — qkvbuf -> h2 (first PLANE)
    // tail: stats(384f) + tvec(3072f) + wbf1/wbf2 (2 x 82944 bf16 = 332KB)
    ushort_t* A  = (ushort_t*)d_ws;
    ushort_t* Bq = A + PLANE_;
    float* stats = (float*)(Bq + 3 * PLANE_);   // 384 floats
    float* tvec  = stats + 384;                 // 3072 floats
    ushort_t* wbf1 = (ushort_t*)(tvec + 3072);  // [9][96][96] bf16
    ushort_t* wbf2 = wbf1 + 82944;

    hipMemsetAsync(stats, 0, 384 * sizeof(float), stream);
    temb_kernel<<<12, 256, 0, stream>>>(t_emb, wt, bt, tvec);
    castw_kernel<<<324, 256, 0, stream>>>(w1, w2, wbf1, wbf2);

    // conv1: x -> y1 (d_out), stats1
    castbf_kernel<<<(int)(PLANE_ / 4 / 256), 256, 0, stream>>>(x, A, (int)(PLANE_ / 4));
    conv3x3_mfma_kernel<<<dim3(2, 64, 16), 256, 0, stream>>>(A, wbf1, b1, out, stats);

    // h = silu(GN(y1))*(1+shift)+bias, in-place on d_out; stats2
    apply1_kernel<<<B_ * C_, 256, 0, stream>>>(out, stats, g1, be1, tvec, out, stats + 128);
    // xq = bf16(GN(h; ga, ba)) -> A
    gn_bf16_kernel<<<B_ * C_, 256, 0, stream>>>(out, stats + 128, ga, ba, A);

    // qkv = conv1x1(xq) -> Bq (288 bf16 planes per batch)
    qkv_gemm_kernel<<<dim3(2, 64, 48), 256, 0, stream>>>(A, qkv_w, qkv_b, Bq);

    // attention: O0 -> A; then A = 0.5*(O0 + O4)
    attn2_kernel<<<dim3(16, 16, 16), 256, 0, stream>>>(Bq, A, 0, 0);
    attn2_kernel<<<dim3(16, 16, 16), 256, 0, stream>>>(Bq, A, 4, 1);

    // h2 = h + proj(A) + pb -> Bq (bf16)
    proj_gemm_kernel<<<dim3(2, 64, 16), 256, 0, stream>>>(A, proj_w, proj_b, out, Bq);

    // conv2: h2 -> y2 (d_out), stats3
    conv3x3_mfma_kernel<<<dim3(2, 64, 16), 256, 0, stream>>>(Bq, wbf2, b2, out, stats + 256);

    // out = silu(GN(y2)), in-place
    gn_apply_kernel<<<B_ * C_, 256, 0, stream>>>(out, stats + 256, g2, be2, out, 1);
}

// Round 2
// 781.868 us; speedup vs baseline: 1.7552x; 1.1116x over previous
//
#include <hip/hip_runtime.h>

// Problem constants
#define B_   16
#define C_   96
#define H_   128
#define W_   128
#define HW_  16384
#define CPG_ 24
#define NPG_ 393216.0f
#define TDIM_ 256
#define PLANE_ ((size_t)B_ * C_ * HW_)   // 25165824

typedef unsigned short ushort_t;
typedef __bf16 bf16x8 __attribute__((ext_vector_type(8)));
typedef float  f32x4  __attribute__((ext_vector_type(4)));
typedef unsigned short u16x8 __attribute__((ext_vector_type(8)));
typedef unsigned short u16x4 __attribute__((ext_vector_type(4)));

#define ICP 104   // padded K-stride in LDS (bf16 elems), 16B-aligned rows

__device__ __forceinline__ float silu_f(float x) { return x / (1.f + __expf(-x)); }
__device__ __forceinline__ float bf2f(ushort_t u) {
    union { float f; unsigned int i; } x; x.i = ((unsigned int)u) << 16; return x.f;
}
__device__ __forceinline__ ushort_t f2bf(float f) {
    __bf16 h = (__bf16)f; return *(ushort_t*)&h;
}

// ---------------------------------------------------------------------------
// t = silu(t_emb @ wt.T + bt) -> tvec[B][192]
// ---------------------------------------------------------------------------
__global__ void temb_kernel(const float* __restrict__ t_emb,
                            const float* __restrict__ wt,
                            const float* __restrict__ bt,
                            float* __restrict__ tvec) {
    int idx = blockIdx.x * 256 + threadIdx.x;
    if (idx >= B_ * 192) return;
    int b = idx / 192, o = idx - b * 192;
    float a = bt[o];
    const float* te = t_emb + b * TDIM_;
    const float* wr = wt + o * TDIM_;
    for (int k = 0; k < TDIM_; ++k) a += te[k] * wr[k];
    tvec[idx] = silu_f(a);
}

// ---------------------------------------------------------------------------
// fp32 -> bf16 cast
// ---------------------------------------------------------------------------
__global__ void castbf_kernel(const float* __restrict__ src,
                              ushort_t* __restrict__ dst, int n4) {
    int i = blockIdx.x * 256 + threadIdx.x;
    if (i >= n4) return;
    float4 v = ((const float4*)src)[i];
    ushort4 u = { f2bf(v.x), f2bf(v.y), f2bf(v.z), f2bf(v.w) };
    ((ushort4*)dst)[i] = u;
}

// ---------------------------------------------------------------------------
// Pre-cast conv weights fp32 [oc][ic][3][3] -> bf16 [kk][oc][ic].
// ---------------------------------------------------------------------------
__global__ void castw_kernel(const float* __restrict__ w1,
                             const float* __restrict__ w2,
                             ushort_t* __restrict__ wbf1,
                             ushort_t* __restrict__ wbf2) {
    int i = blockIdx.x * 256 + threadIdx.x;
    int ic = i % 96;
    int t  = i / 96;
    int oc = t % 96;
    int kk = t / 96;
    int src = (oc * 96 + ic) * 9 + kk;
    wbf1[i] = f2bf(w1[src]);
    wbf2[i] = f2bf(w2[src]);
}

// ---------------------------------------------------------------------------
// conv3x3 implicit-GEMM MFMA + bias + GN stats. (verified in R1; unchanged)
// ---------------------------------------------------------------------------
__global__ __launch_bounds__(256, 2)
void conv3x3_mfma_kernel(const ushort_t* __restrict__ xbf,
                         const ushort_t* __restrict__ wbf,   // [9][96][96] bf16
                         const float* __restrict__ bias,
                         float* __restrict__ out,
                         float* __restrict__ stats) {
    __shared__ __align__(16) ushort_t ti[4 * 66 * ICP];
    __shared__ __align__(16) ushort_t wc[96 * ICP];
    __shared__ float red[4][96][2];

    const int b   = blockIdx.z;
    const int y0  = blockIdx.y * 2;
    const int x0  = blockIdx.x * 64;
    const int tid = threadIdx.x;
    const int wv   = tid >> 6;
    const int lane = tid & 63;
    const int l15  = lane & 15;
    const int quad = lane >> 4;

    // ---- interior input staging: tasks (r,xc,ic) = 4*8*96 = 3072, 12 iters
#pragma unroll
    for (int it = 0; it < 12; ++it) {
        int idx = it * 256 + tid;
        int ic = idx % 96;           // consecutive lanes -> consecutive ic
        int t2 = idx / 96;
        int xc = t2 & 7;
        int r  = t2 >> 3;
        int gy = y0 - 1 + r;
        u16x8 v = {};
        if (gy >= 0 && gy < H_)
            v = *(const u16x8*)&xbf[((b * 96 + ic) * H_ + gy) * W_ + x0 + xc * 8];
        ushort_t* dst = &ti[(r * 66 + xc * 8 + 1) * ICP + ic];
#pragma unroll
        for (int j = 0; j < 8; ++j) dst[j * ICP] = v[j];
    }
    // ---- halo columns xi=0 (gx=x0-1) and xi=65 (gx=x0+64): 768 scalar elems
    {
        int idx = tid;
#pragma unroll
        for (int it = 0; it < 3; ++it, idx += 256) {
            int ic = idx % 96;
            int t2 = idx / 96;       // 0..7
            int r = t2 >> 1, side = t2 & 1;
            int xi = side ? 65 : 0;
            int gx = x0 - 1 + xi;
            int gy = y0 - 1 + r;
            ushort_t vv = 0;
            if (gy >= 0 && gy < H_ && gx >= 0 && gx < W_)
                vv = xbf[((b * 96 + ic) * H_ + gy) * W_ + gx];
            ti[(r * 66 + xi) * ICP + ic] = vv;
        }
    }

    // ---- per-thread weight-staging task table (loop-invariant offsets)
    int wsrc[5], wdst[5];
#pragma unroll
    for (int i = 0; i < 5; ++i) {
        int idx = tid + i * 256;
        int icb = idx % 12;
        int oc  = idx / 12;
        wsrc[i] = oc * 96 + icb * 8;
        wdst[i] = oc * ICP + icb * 8;
    }
    u16x8 wreg[5];
#pragma unroll
    for (int i = 0; i < 4; ++i) wreg[i] = *(const u16x8*)&wbf[wsrc[i]];
    if (tid < 128) wreg[4] = *(const u16x8*)&wbf[wsrc[4]];

    f32x4 acc[2][6];
#pragma unroll
    for (int m = 0; m < 2; ++m)
#pragma unroll
        for (int nt = 0; nt < 6; ++nt)
            acc[m][nt] = (f32x4){0.f, 0.f, 0.f, 0.f};

    for (int kk = 0; kk < 9; ++kk) {
        const int ky = kk / 3, kx = kk - ky * 3;
        __syncthreads();   // prev compute done reading wc (covers ti at kk=0)
#pragma unroll
        for (int i = 0; i < 4; ++i) *(u16x8*)&wc[wdst[i]] = wreg[i];
        if (tid < 128) *(u16x8*)&wc[wdst[4]] = wreg[4];
        __syncthreads();
        if (kk < 8) {      // prefetch next kk's weights; completes under MFMA
            const ushort_t* wsk = wbf + (kk + 1) * 9216;
#pragma unroll
            for (int i = 0; i < 4; ++i) wreg[i] = *(const u16x8*)&wsk[wsrc[i]];
            if (tid < 128) wreg[4] = *(const u16x8*)&wsk[wsrc[4]];
        }
#pragma unroll 1
        for (int ck = 0; ck < 3; ++ck) {
            const int kbase = ck * 32 + quad * 8;
            bf16x8 a0 = *(const bf16x8*)&ti[((0 + ky) * 66 + (wv * 16 + l15 + kx)) * ICP + kbase];
            bf16x8 a1 = *(const bf16x8*)&ti[((1 + ky) * 66 + (wv * 16 + l15 + kx)) * ICP + kbase];
#pragma unroll
            for (int nt = 0; nt < 6; ++nt) {
                bf16x8 bv = *(const bf16x8*)&wc[(nt * 16 + l15) * ICP + kbase];
                acc[0][nt] = __builtin_amdgcn_mfma_f32_16x16x32_bf16(a0, bv, acc[0][nt], 0, 0, 0);
                acc[1][nt] = __builtin_amdgcn_mfma_f32_16x16x32_bf16(a1, bv, acc[1][nt], 0, 0, 0);
            }
        }
    }

    float lsum[6], lsq[6];
#pragma unroll
    for (int nt = 0; nt < 6; ++nt) { lsum[nt] = 0.f; lsq[nt] = 0.f; }

#pragma unroll
    for (int m = 0; m < 2; ++m) {
        const int gy = y0 + m;
        const int gx = x0 + wv * 16 + quad * 4;
#pragma unroll
        for (int nt = 0; nt < 6; ++nt) {
            const int oc = nt * 16 + l15;
            const float bz = bias[oc];
            float v0 = acc[m][nt][0] + bz;
            float v1 = acc[m][nt][1] + bz;
            float v2 = acc[m][nt][2] + bz;
            float v3 = acc[m][nt][3] + bz;
            float4 vv = make_float4(v0, v1, v2, v3);
            *(float4*)&out[((b * 96 + oc) * H_ + gy) * W_ + gx] = vv;
            lsum[nt] += v0 + v1 + v2 + v3;
            lsq[nt]  += v0 * v0 + v1 * v1 + v2 * v2 + v3 * v3;
        }
    }
#pragma unroll
    for (int nt = 0; nt < 6; ++nt) {
        float s = lsum[nt], q = lsq[nt];
        s += __shfl_down(s, 32, 64);
        s += __shfl_down(s, 16, 64);
        q += __shfl_down(q, 32, 64);
        q += __shfl_down(q, 16, 64);
        if (lane < 16) {
            red[wv][nt * 16 + lane][0] = s;
            red[wv][nt * 16 + lane][1] = q;
        }
    }
    __syncthreads();
    if (tid < 8) {
        const int g = tid >> 1, which = tid & 1;
        float v = 0.f;
        for (int oc = g * CPG_; oc < g * CPG_ + CPG_; ++oc)
            for (int w2 = 0; w2 < 4; ++w2) v += red[w2][oc][which];
        atomicAdd(&stats[(b * 4 + g) * 2 + which], v);
    }
}

// ---------------------------------------------------------------------------
// h = silu(GN(y)) * (1+shift) + bias  (IN-PLACE on d_out), emits stats2
// ---------------------------------------------------------------------------
__global__ void apply1_kernel(const float* y,
                              const float* __restrict__ stats1,
                              const float* __restrict__ g1,
                              const float* __restrict__ be1,
                              const float* __restrict__ tvec,
                              float* h,
                              float* __restrict__ stats2) {
    const int bc = blockIdx.x;
    const int b = bc / C_, c = bc - b * C_;
    const int g = c / CPG_;
    const float sum = stats1[(b * 4 + g) * 2], sumsq = stats1[(b * 4 + g) * 2 + 1];
    const float mean = sum / NPG_;
    const float var  = sumsq / NPG_ - mean * mean;
    const float rstd = rsqrtf(var + 1e-5f);
    const float sc = rstd * g1[c];
    const float sh = be1[c] - mean * sc;
    const float tsc = 1.f + tvec[b * 192 + c];
    const float tbi = tvec[b * 192 + 96 + c];

    const float4* yp = (const float4*)(y + (size_t)bc * HW_);
    float4* hp = (float4*)(h + (size_t)bc * HW_);
    float ls = 0.f, lss = 0.f;
    for (int i = threadIdx.x; i < HW_ / 4; i += 256) {
        float4 v = yp[i];
        float r0 = silu_f(v.x * sc + sh) * tsc + tbi;
        float r1 = silu_f(v.y * sc + sh) * tsc + tbi;
        float r2 = silu_f(v.z * sc + sh) * tsc + tbi;
        float r3 = silu_f(v.w * sc + sh) * tsc + tbi;
        hp[i] = make_float4(r0, r1, r2, r3);
        ls  += r0 + r1 + r2 + r3;
        lss += r0*r0 + r1*r1 + r2*r2 + r3*r3;
    }
    for (int off = 32; off > 0; off >>= 1) {
        ls  += __shfl_down(ls, off, 64);
        lss += __shfl_down(lss, off, 64);
    }
    if ((threadIdx.x & 63) == 0) {
        atomicAdd(&stats2[(b * 4 + g) * 2 + 0], ls);
        atomicAdd(&stats2[(b * 4 + g) * 2 + 1], lss);
    }
}

// ---------------------------------------------------------------------------
// GN apply -> bf16 output (qkv GEMM input)
// ---------------------------------------------------------------------------
__global__ void gn_bf16_kernel(const float* __restrict__ in,
                               const float* __restrict__ stats,
                               const float* __restrict__ gamma,
                               const float* __restrict__ beta,
                               ushort_t* __restrict__ outb) {
    const int bc = blockIdx.x;
    const int b = bc / C_, c = bc - b * C_;
    const int g = c / CPG_;
    const float sum = stats[(b * 4 + g) * 2], sumsq = stats[(b * 4 + g) * 2 + 1];
    const float mean = sum / NPG_;
    const float var  = sumsq / NPG_ - mean * mean;
    const float rstd = rsqrtf(var + 1e-5f);
    const float sc = rstd * gamma[c];
    const float sh = beta[c] - mean * sc;
    const float4* ip = (const float4*)(in + (size_t)bc * HW_);
    ushort4* op = (ushort4*)(outb + (size_t)bc * HW_);
    for (int i = threadIdx.x; i < HW_ / 4; i += 256) {
        float4 v = ip[i];
        ushort4 u = { f2bf(v.x * sc + sh), f2bf(v.y * sc + sh),
                      f2bf(v.z * sc + sh), f2bf(v.w * sc + sh) };
        op[i] = u;
    }
}

// ---------------------------------------------------------------------------
// GN apply fp32 (+silu), in-place capable
// ---------------------------------------------------------------------------
__global__ void gn_apply_kernel(const float* in,
                                const float* __restrict__ stats,
                                const float* __restrict__ gamma,
                                const float* __restrict__ beta,
                                float* out, int dosilu) {
    const int bc = blockIdx.x;
    const int b = bc / C_, c = bc - b * C_;
    const int g = c / CPG_;
    const float sum = stats[(b * 4 + g) * 2], sumsq = stats[(b * 4 + g) * 2 + 1];
    const float mean = sum / NPG_;
    const float var  = sumsq / NPG_ - mean * mean;
    const float rstd = rsqrtf(var + 1e-5f);
    const float sc = rstd * gamma[c];
    const float sh = beta[c] - mean * sc;
    const float4* ip = (const float4*)(in + (size_t)bc * HW_);
    float4* op = (float4*)(out + (size_t)bc * HW_);
    for (int i = threadIdx.x; i < HW_ / 4; i += 256) {
        float4 v = ip[i];
        float r0 = v.x * sc + sh, r1 = v.y * sc + sh;
        float r2 = v.z * sc + sh, r3 = v.w * sc + sh;
        if (dosilu) { r0 = silu_f(r0); r1 = silu_f(r1); r2 = silu_f(r2); r3 = silu_f(r3); }
        op[i] = make_float4(r0, r1, r2, r3);
    }
}

// ---------------------------------------------------------------------------
// qkv 1x1 GEMM (verified in R1; unchanged)
// ---------------------------------------------------------------------------
__global__ __launch_bounds__(256, 3)
void qkv_gemm_kernel(const ushort_t* __restrict__ xq,
                     const float* __restrict__ qw,   // [288][96]
                     const float* __restrict__ qb,
                     ushort_t* __restrict__ qkvbuf) {
    __shared__ __align__(16) ushort_t ti[2 * 64 * ICP];
    __shared__ __align__(16) ushort_t wc[96 * ICP];

    const int bz = blockIdx.z;
    const int b = bz / 3, s = bz - b * 3;
    const int y0 = blockIdx.y * 2;
    const int x0 = blockIdx.x * 64;
    const int tid = threadIdx.x;
    const int wv = tid >> 6, lane = tid & 63;
    const int l15 = lane & 15, quad = lane >> 4;

#pragma unroll
    for (int it = 0; it < 6; ++it) {
        int idx = it * 256 + tid;
        int ic = idx % 96;
        int t2 = idx / 96;
        int xc = t2 & 7;
        int r  = t2 >> 3;
        u16x8 v = *(const u16x8*)&xq[((b * 96 + ic) * H_ + y0 + r) * W_ + x0 + xc * 8];
        ushort_t* dst = &ti[(r * 64 + xc * 8) * ICP + ic];
#pragma unroll
        for (int j = 0; j < 8; ++j) dst[j * ICP] = v[j];
    }
#pragma unroll
    for (int it = 0; it < 9; ++it) {
        int idx = it * 256 + tid;
        int icq = idx % 24;
        int oc  = idx / 24;
        float4 wv4 = *(const float4*)&qw[(s * 96 + oc) * 96 + icq * 4];
        ushort4 u = { f2bf(wv4.x), f2bf(wv4.y), f2bf(wv4.z), f2bf(wv4.w) };
        *(ushort4*)&wc[oc * ICP + icq * 4] = u;
    }
    __syncthreads();

    f32x4 acc[2][6];
#pragma unroll
    for (int m = 0; m < 2; ++m)
#pragma unroll
        for (int nt = 0; nt < 6; ++nt) acc[m][nt] = (f32x4){0.f, 0.f, 0.f, 0.f};

#pragma unroll
    for (int ck = 0; ck < 3; ++ck) {
        const int kbase = ck * 32 + quad * 8;
        bf16x8 a0 = *(const bf16x8*)&ti[(0 * 64 + wv * 16 + l15) * ICP + kbase];
        bf16x8 a1 = *(const bf16x8*)&ti[(1 * 64 + wv * 16 + l15) * ICP + kbase];
#pragma unroll
        for (int nt = 0; nt < 6; ++nt) {
            bf16x8 bv = *(const bf16x8*)&wc[(nt * 16 + l15) * ICP + kbase];
            acc[0][nt] = __builtin_amdgcn_mfma_f32_16x16x32_bf16(a0, bv, acc[0][nt], 0, 0, 0);
            acc[1][nt] = __builtin_amdgcn_mfma_f32_16x16x32_bf16(a1, bv, acc[1][nt], 0, 0, 0);
        }
    }

#pragma unroll
    for (int m = 0; m < 2; ++m) {
        const int gy = y0 + m;
        const int gx = x0 + wv * 16 + quad * 4;
#pragma unroll
        for (int nt = 0; nt < 6; ++nt) {
            const int ocg = s * 96 + nt * 16 + l15;
            const float bz2 = qb[ocg];
            ushort4 u = { f2bf(acc[m][nt][0] + bz2), f2bf(acc[m][nt][1] + bz2),
                          f2bf(acc[m][nt][2] + bz2), f2bf(acc[m][nt][3] + bz2) };
            *(ushort4*)&qkvbuf[((size_t)(b * 288 + ocg) * H_ + gy) * W_ + gx] = u;
        }
    }
}

// ---------------------------------------------------------------------------
// Attention v3: same verified MFMA math as v2, staging reworked:
//  - Q/K staged into qk with padded strides: row stride 160 el (320B, 16 dw
//    mod 32) and channel stride 1288 el (4 dw mod 32) -> S^T fragment reads
//    drop from 4-way bank conflict to <=2-way (free).
//  - V staged linearly into ost (dead until PV epilogue) with the same
//    vectorized 8B writes as Q/K, then transposed LDS->LDS: each thread reads
//    6 x ushort4 (conflict-free) and writes 4 x b128 [px][d0..5,0,0] slots.
//    Replaces 24 scalar 8-way-conflicted b16 writes/thread, writes the zero
//    slots explicitly, and removes the 16-iter vt zeroing pass entirely.
//  - vt window stride padded 512 -> 520 el.
// ---------------------------------------------------------------------------
#define QKC 1288   // qk channel stride (elems): 2576B = 644 dw == 4 mod 32
#define QKR 160    // qk row stride (elems):      320B =  80 dw == 16 mod 32
#define OSTS 1032  // ost/vrow channel stride (elems)
#define VTS 520    // vt per-window stride (elems): 1040B = 260 dw == 4 mod 32
__global__ __launch_bounds__(256, 2)
void attn2_kernel(const ushort_t* __restrict__ qkv,
                  ushort_t* __restrict__ obuf, int shift, int accumulate) {
    __shared__ __align__(16) ushort_t qk[12 * QKC];        // Q d=0..5, K d=6..11
    __shared__ __align__(16) ushort_t vt[16 * VTS + 32];   // [wx][px][8] slots
    __shared__ __align__(16) ushort_t ost[6 * OSTS];       // V rows, then O staging

    const int h = blockIdx.x, wy = blockIdx.y, b = blockIdx.z;
    const int tid = threadIdx.x;
    const int wv = tid >> 6, lane = tid & 63;
    const int l15 = lane & 15, quad = lane >> 4;

    // stage: 18 ch x 8 rows x 16 x-chunks of 8 px. Q/K -> qk, V rows -> ost.
    for (int idx = tid; idx < 2304; idx += 256) {
        int xc = idx & 15;
        int t2 = idx >> 4;
        int r  = t2 & 7;
        int ch = t2 >> 3;                 // 0..17
        int part = ch / 6, d = ch - part * 6;
        int gch = part * 96 + h * 6 + d;  // q / k / v plane
        int gy = (wy * 8 + r + shift) & 127;
        size_t rowb = ((size_t)(b * 288 + gch) * H_ + gy) * W_;
        ushort4 u0, u1;
        if (shift == 0) {
            u0 = *(const ushort4*)&qkv[rowb + xc * 8];
            u1 = *(const ushort4*)&qkv[rowb + xc * 8 + 4];
        } else {
            u0 = *(const ushort4*)&qkv[rowb + ((xc * 8 + 4) & 127)];
            u1 = *(const ushort4*)&qkv[rowb + ((xc * 8 + 8) & 127)];
        }
        ushort_t* dst = (part < 2) ? &qk[ch * QKC + r * QKR + xc * 8]
                                   : &ost[d * OSTS + r * 128 + xc * 8];
        *(ushort4*)dst = u0;
        *(ushort4*)(dst + 4) = u1;
    }
    __syncthreads();

    // transpose V: ost[d][r*128+x] -> vt[wx][r*8+(x&7)][d], zero slots 6,7.
    {
        const int r   = tid >> 5;        // 0..7
        const int pxq = tid & 31;        // 0..31
        const int px  = pxq * 4;
        u16x4 vv[6];
#pragma unroll
        for (int c = 0; c < 6; ++c)
            vv[c] = *(const u16x4*)&ost[c * OSTS + r * 128 + px];
        const int wx = px >> 3;
        const int p7 = px & 7;           // 0 or 4
#pragma unroll
        for (int j = 0; j < 4; ++j) {
            u16x8 t;
            t[0] = vv[0][j]; t[1] = vv[1][j]; t[2] = vv[2][j];
            t[3] = vv[3][j]; t[4] = vv[4][j]; t[5] = vv[5][j];
            t[6] = 0; t[7] = 0;
            *(u16x8*)&vt[wx * VTS + (r * 8 + p7 + j) * 8] = t;
        }
        if (tid < 16) ((unsigned int*)(vt + 16 * VTS))[tid] = 0u;  // tail pad
    }
    __syncthreads();

    const float scale = 0.40824829046386302f;  // 6^-0.5
    const int dcl = (l15 < 6) ? l15 : 5;       // clamp garbage lanes in-bounds
    const int chA = 6 + dcl;                   // K row e
    const int chB = dcl;                       // Q row d

    for (int i = 0; i < 4; ++i) {
        const int wx = wv * 4 + i;
        // ---- S^T = K Q^T (m=e, n=d, k=px)
        f32x4 sa = (f32x4){0.f, 0.f, 0.f, 0.f};
#pragma unroll
        for (int ck = 0; ck < 2; ++ck) {
            const int r = ck * 4 + quad;
            bf16x8 af  = *(const bf16x8*)&qk[chA * QKC + r * QKR + wx * 8];
            bf16x8 bfv = *(const bf16x8*)&qk[chB * QKC + r * QKR + wx * 8];
            sa = __builtin_amdgcn_mfma_f32_16x16x32_bf16(af, bfv, sa, 0, 0, 0);
        }
        float s0 = sa[0] * scale, s1 = sa[1] * scale, s2 = sa[2] * scale, s3 = sa[3] * scale;
        float m = -3.4e38f;
        if (quad == 0) m = fmaxf(fmaxf(s0, s1), fmaxf(s2, s3));
        else if (quad == 1) m = fmaxf(s0, s1);
        m = fmaxf(m, __shfl_xor(m, 16, 64));
        m = fmaxf(m, __shfl_xor(m, 32, 64));
        float p0 = (quad <= 1) ? __expf(s0 - m) : 0.f;
        float p1 = (quad <= 1) ? __expf(s1 - m) : 0.f;
        float p2 = (quad == 0) ? __expf(s2 - m) : 0.f;
        float p3 = (quad == 0) ? __expf(s3 - m) : 0.f;
        float sum = p0 + p1 + p2 + p3;
        sum += __shfl_xor(sum, 16, 64);
        sum += __shfl_xor(sum, 32, 64);
        float inv = 1.f / sum;
        p0 *= inv; p1 *= inv; p2 *= inv; p3 *= inv;
        float e4 = __shfl_xor(p0, 16, 64);
        float e5 = __shfl_xor(p1, 16, 64);
        bf16x8 pf;
        pf[0] = (__bf16)p0; pf[1] = (__bf16)p1; pf[2] = (__bf16)p2; pf[3] = (__bf16)p3;
        pf[4] = (__bf16)e4; pf[5] = (__bf16)e5;
        pf[6] = (__bf16)0.f; pf[7] = (__bf16)0.f;
        if (quad != 0) { bf16x8 z = {}; pf = z; }
        // ---- O^T tiles: m=px (4 tiles of 16), n=d
#pragma unroll
        for (int mt = 0; mt < 4; ++mt) {
            bf16x8 av = *(const bf16x8*)&vt[wx * VTS + (mt * 16 + l15) * 8 + quad * 8];
            f32x4 o = __builtin_amdgcn_mfma_f32_16x16x32_bf16(av, pf, (f32x4){0.f,0.f,0.f,0.f}, 0, 0, 0);
            if (l15 < 6) {
                const int px = mt * 16 + quad * 4;
                const int r = px >> 3, c = px & 7;
                ushort4 st = { f2bf(o[0]), f2bf(o[1]), f2bf(o[2]), f2bf(o[3]) };
                *(ushort4*)&ost[l15 * OSTS + r * 128 + wx * 8 + c] = st;
            }
        }
    }
    __syncthreads();

    // coalesced write-out: 6 ch x 8 rows x 16 chunks
    for (int idx = tid; idx < 768; idx += 256) {
        int xc = idx & 15;
        int t2 = idx >> 4;
        int r = t2 & 7, d = t2 >> 3;
        int gy = (wy * 8 + r + shift) & 127;
        size_t rowb = ((size_t)(b * 96 + h * 6 + d) * H_ + gy) * W_;
        size_t a0, a1;
        if (shift == 0) { a0 = rowb + xc * 8; a1 = rowb + xc * 8 + 4; }
        else { a0 = rowb + ((xc * 8 + 4) & 127); a1 = rowb + ((xc * 8 + 8) & 127); }
        const ushort_t* src = &ost[d * OSTS + r * 128 + xc * 8];
        ushort4 v0 = *(const ushort4*)src;
        ushort4 v1 = *(const ushort4*)(src + 4);
        if (accumulate) {
            ushort4 q0 = *(const ushort4*)&obuf[a0];
            ushort4 q1 = *(const ushort4*)&obuf[a1];
            v0.x = f2bf(0.5f * (bf2f(v0.x) + bf2f(q0.x)));
            v0.y = f2bf(0.5f * (bf2f(v0.y) + bf2f(q0.y)));
            v0.z = f2bf(0.5f * (bf2f(v0.z) + bf2f(q0.z)));
            v0.w = f2bf(0.5f * (bf2f(v0.w) + bf2f(q0.w)));
            v1.x = f2bf(0.5f * (bf2f(v1.x) + bf2f(q1.x)));
            v1.y = f2bf(0.5f * (bf2f(v1.y) + bf2f(q1.y)));
            v1.z = f2bf(0.5f * (bf2f(v1.z) + bf2f(q1.z)));
            v1.w = f2bf(0.5f * (bf2f(v1.w) + bf2f(q1.w)));
        }
        *(ushort4*)&obuf[a0] = v0;
        *(ushort4*)&obuf[a1] = v1;
    }
}

// ---------------------------------------------------------------------------
// proj 1x1 GEMM + residual add (verified in R1; unchanged)
// ---------------------------------------------------------------------------
__global__ __launch_bounds__(256, 3)
void proj_gemm_kernel(const ushort_t* __restrict__ ob,
                      const float* __restrict__ pw,   // [96][96]
                      const float* __restrict__ pb,
                      const float* __restrict__ resid,
                      ushort_t* __restrict__ h2) {
    __shared__ __align__(16) ushort_t ti[2 * 64 * ICP];
    __shared__ __align__(16) ushort_t wc[96 * ICP];

    const int b = blockIdx.z;
    const int y0 = blockIdx.y * 2;
    const int x0 = blockIdx.x * 64;
    const int tid = threadIdx.x;
    const int wv = tid >> 6, lane = tid & 63;
    const int l15 = lane & 15, quad = lane >> 4;

#pragma unroll
    for (int it = 0; it < 6; ++it) {
        int idx = it * 256 + tid;
        int ic = idx % 96;
        int t2 = idx / 96;
        int xc = t2 & 7;
        int r  = t2 >> 3;
        u16x8 v = *(const u16x8*)&ob[((b * 96 + ic) * H_ + y0 + r) * W_ + x0 + xc * 8];
        ushort_t* dst = &ti[(r * 64 + xc * 8) * ICP + ic];
#pragma unroll
        for (int j = 0; j < 8; ++j) dst[j * ICP] = v[j];
    }
#pragma unroll
    for (int it = 0; it < 9; ++it) {
        int idx = it * 256 + tid;
        int icq = idx % 24;
        int oc  = idx / 24;
        float4 wv4 = *(const float4*)&pw[oc * 96 + icq * 4];
        ushort4 u = { f2bf(wv4.x), f2bf(wv4.y), f2bf(wv4.z), f2bf(wv4.w) };
        *(ushort4*)&wc[oc * ICP + icq * 4] = u;
    }
    __syncthreads();

    f32x4 acc[2][6];
#pragma unroll
    for (int m = 0; m < 2; ++m)
#pragma unroll
        for (int nt = 0; nt < 6; ++nt) acc[m][nt] = (f32x4){0.f, 0.f, 0.f, 0.f};

#pragma unroll
    for (int ck = 0; ck < 3; ++ck) {
        const int kbase = ck * 32 + quad * 8;
        bf16x8 a0 = *(const bf16x8*)&ti[(0 * 64 + wv * 16 + l15) * ICP + kbase];
        bf16x8 a1 = *(const bf16x8*)&ti[(1 * 64 + wv * 16 + l15) * ICP + kbase];
#pragma unroll
        for (int nt = 0; nt < 6; ++nt) {
            bf16x8 bv = *(const bf16x8*)&wc[(nt * 16 + l15) * ICP + kbase];
            acc[0][nt] = __builtin_amdgcn_mfma_f32_16x16x32_bf16(a0, bv, acc[0][nt], 0, 0, 0);
            acc[1][nt] = __builtin_amdgcn_mfma_f32_16x16x32_bf16(a1, bv, acc[1][nt], 0, 0, 0);
        }
    }

#pragma unroll
    for (int m = 0; m < 2; ++m) {
        const int gy = y0 + m;
        const int gx = x0 + wv * 16 + quad * 4;
#pragma unroll
        for (int nt = 0; nt < 6; ++nt) {
            const int oc = nt * 16 + l15;
            const float bz2 = pb[oc];
            size_t addr = ((size_t)(b * 96 + oc) * H_ + gy) * W_ + gx;
            float4 rv = *(const float4*)&resid[addr];
            ushort4 u = { f2bf(acc[m][nt][0] + bz2 + rv.x),
                          f2bf(acc[m][nt][1] + bz2 + rv.y),
                          f2bf(acc[m][nt][2] + bz2 + rv.z),
                          f2bf(acc[m][nt][3] + bz2 + rv.w) };
            *(ushort4*)&h2[addr] = u;
        }
    }
}

// ---------------------------------------------------------------------------
extern "C" void kernel_launch(void* const* d_in, const int* in_sizes, int n_in,
                              void* d_out, int out_size, void* d_ws, size_t ws_size,
                              hipStream_t stream) {
    const float* x     = (const float*)d_in[0];
    const float* t_emb = (const float*)d_in[1];
    const float* w1    = (const float*)d_in[2];
    const float* b1    = (const float*)d_in[3];
    const float* g1    = (const float*)d_in[4];
    const float* be1   = (const float*)d_in[5];
    const float* wt    = (const float*)d_in[6];
    const float* bt    = (const float*)d_in[7];
    const float* qkv_w = (const float*)d_in[8];
    const float* qkv_b = (const float*)d_in[9];
    const float* proj_w= (const float*)d_in[10];
    const float* proj_b= (const float*)d_in[11];
    const float* ga    = (const float*)d_in[12];
    const float* ba    = (const float*)d_in[13];
    const float* w2    = (const float*)d_in[14];
    const float* b2    = (const float*)d_in[15];
    const float* g2    = (const float*)d_in[16];
    const float* be2   = (const float*)d_in[17];

    float* out = (float*)d_out;

    // Workspace arena:
    // A: PLANE bf16  — xbf1 -> xq -> Obuf
    // B: 3*PLANE bf16 — qkvbuf -> h2 (first PLANE)
    // tail: stats(384f) + tvec(3072f) + wbf1/wbf2 (2 x 82944 bf16)
    ushort_t* A  = (ushort_t*)d_ws;
    ushort_t* Bq = A + PLANE_;
    float* stats = (float*)(Bq + 3 * PLANE_);   // 384 floats
    float* tvec  = stats + 384;                 // 3072 floats
    ushort_t* wbf1 = (ushort_t*)(tvec + 3072);  // [9][96][96] bf16
    ushort_t* wbf2 = wbf1 + 82944;

    hipMemsetAsync(stats, 0, 384 * sizeof(float), stream);
    temb_kernel<<<12, 256, 0, stream>>>(t_emb, wt, bt, tvec);
    castw_kernel<<<324, 256, 0, stream>>>(w1, w2, wbf1, wbf2);

    // conv1: x -> y1 (d_out), stats1
    castbf_kernel<<<(int)(PLANE_ / 4 / 256), 256, 0, stream>>>(x, A, (int)(PLANE_ / 4));
    conv3x3_mfma_kernel<<<dim3(2, 64, 16), 256, 0, stream>>>(A, wbf1, b1, out, stats);

    // h = silu(GN(y1))*(1+shift)+bias, in-place on d_out; stats2
    apply1_kernel<<<B_ * C_, 256, 0, stream>>>(out, stats, g1, be1, tvec, out, stats + 128);
    // xq = bf16(GN(h; ga, ba)) -> A
    gn_bf16_kernel<<<B_ * C_, 256, 0, stream>>>(out, stats + 128, ga, ba, A);

    // qkv = conv1x1(xq) -> Bq (288 bf16 planes per batch)
    qkv_gemm_kernel<<<dim3(2, 64, 48), 256, 0, stream>>>(A, qkv_w, qkv_b, Bq);

    // attention: O0 -> A; then A = 0.5*(O0 + O4)
    attn2_kernel<<<dim3(16, 16, 16), 256, 0, stream>>>(Bq, A, 0, 0);
    attn2_kernel<<<dim3(16, 16, 16), 256, 0, stream>>>(Bq, A, 4, 1);

    // h2 = h + proj(A) + pb -> Bq (bf16)
    proj_gemm_kernel<<<dim3(2, 64, 16), 256, 0, stream>>>(A, proj_w, proj_b, out, Bq);

    // conv2: h2 -> y2 (d_out), stats3
    conv3x3_mfma_kernel<<<dim3(2, 64, 16), 256, 0, stream>>>(Bq, wbf2, b2, out, stats + 256);

    // out = silu(GN(y2)), in-place
    gn_apply_kernel<<<B_ * C_, 256, 0, stream>>>(out, stats + 256, g2, be2, out, 1);
}

// Round 3
// 727.082 us; speedup vs baseline: 1.8875x; 1.0754x over previous
//
#include <hip/hip_runtime.h>

// Problem constants
#define B_   16
#define C_   96
#define H_   128
#define W_   128
#define HW_  16384
#define CPG_ 24
#define NPG_ 393216.0f
#define TDIM_ 256
#define PLANE_ ((size_t)B_ * C_ * HW_)   // 25165824

typedef unsigned short ushort_t;
typedef __bf16 bf16x8 __attribute__((ext_vector_type(8)));
typedef float  f32x4  __attribute__((ext_vector_type(4)));
typedef unsigned short u16x8 __attribute__((ext_vector_type(8)));
typedef unsigned short u16x4 __attribute__((ext_vector_type(4)));

#define ICP 104   // padded K-stride in LDS (bf16 elems), 16B-aligned rows

__device__ __forceinline__ float silu_f(float x) { return x / (1.f + __expf(-x)); }
__device__ __forceinline__ float bf2f(ushort_t u) {
    union { float f; unsigned int i; } x; x.i = ((unsigned int)u) << 16; return x.f;
}
__device__ __forceinline__ ushort_t f2bf(float f) {
    __bf16 h = (__bf16)f; return *(ushort_t*)&h;
}

// ---------------------------------------------------------------------------
// t = silu(t_emb @ wt.T + bt) -> tvec[B][192]
// ---------------------------------------------------------------------------
__global__ void temb_kernel(const float* __restrict__ t_emb,
                            const float* __restrict__ wt,
                            const float* __restrict__ bt,
                            float* __restrict__ tvec) {
    int idx = blockIdx.x * 256 + threadIdx.x;
    if (idx >= B_ * 192) return;
    int b = idx / 192, o = idx - b * 192;
    float a = bt[o];
    const float* te = t_emb + b * TDIM_;
    const float* wr = wt + o * TDIM_;
    for (int k = 0; k < TDIM_; ++k) a += te[k] * wr[k];
    tvec[idx] = silu_f(a);
}

// ---------------------------------------------------------------------------
// Pre-cast conv weights fp32 [oc][ic][3][3] -> bf16 [kk][oc][ic].
// ---------------------------------------------------------------------------
__global__ void castw_kernel(const float* __restrict__ w1,
                             const float* __restrict__ w2,
                             ushort_t* __restrict__ wbf1,
                             ushort_t* __restrict__ wbf2) {
    int i = blockIdx.x * 256 + threadIdx.x;
    int ic = i % 96;
    int t  = i / 96;
    int oc = t % 96;
    int kk = t / 96;
    int src = (oc * 96 + ic) * 9 + kk;
    wbf1[i] = f2bf(w1[src]);
    wbf2[i] = f2bf(w2[src]);
}

// ---------------------------------------------------------------------------
// Stage one input row (gy) into ti2 ring slot: interior 768 tasks (3 iters,
// lanes = consecutive ic -> conflict-free transposed b16 writes) + 192 halo.
// FP32=1 reads fp32 and casts in-flight (conv1); FP32=0 reads bf16 (conv2).
// No internal barriers - all threads participate uniformly.
// ---------------------------------------------------------------------------
template<int FP32>
__device__ __forceinline__ void stage_row(const void* __restrict__ xin,
                                          ushort_t* __restrict__ ti2,
                                          int b, int gy, int x0, int slot, int tid) {
    const bool rowok = (gy >= 0 && gy < H_);
#pragma unroll
    for (int it = 0; it < 3; ++it) {
        int idx = it * 256 + tid;
        int ic = idx % 96;           // consecutive lanes -> consecutive ic
        int xc = idx / 96;           // 0..7
        u16x8 v = {};
        if (rowok) {
            if (FP32) {
                const float* xf = (const float*)xin;
                const float4* p = (const float4*)&xf[((size_t)(b * 96 + ic) * H_ + gy) * W_ + x0 + xc * 8];
                float4 f0 = p[0], f1 = p[1];
                v[0] = f2bf(f0.x); v[1] = f2bf(f0.y); v[2] = f2bf(f0.z); v[3] = f2bf(f0.w);
                v[4] = f2bf(f1.x); v[5] = f2bf(f1.y); v[6] = f2bf(f1.z); v[7] = f2bf(f1.w);
            } else {
                const ushort_t* xb = (const ushort_t*)xin;
                v = *(const u16x8*)&xb[((size_t)(b * 96 + ic) * H_ + gy) * W_ + x0 + xc * 8];
            }
        }
        ushort_t* dst = &ti2[(slot * 66 + xc * 8 + 1) * ICP + ic];
#pragma unroll
        for (int j = 0; j < 8; ++j) dst[j * ICP] = v[j];
    }
    if (tid < 192) {
        int ic = tid % 96;
        int side = tid / 96;         // 0,1
        int xi = side ? 65 : 0;
        int gx = x0 - 1 + xi;
        ushort_t vv = 0;
        if (rowok && gx >= 0 && gx < W_) {
            if (FP32) vv = f2bf(((const float*)xin)[((size_t)(b * 96 + ic) * H_ + gy) * W_ + gx]);
            else      vv = ((const ushort_t*)xin)[((size_t)(b * 96 + ic) * H_ + gy) * W_ + gx];
        }
        ti2[(slot * 66 + xi) * ICP + ic] = vv;
    }
}

// ---------------------------------------------------------------------------
// conv3x3 implicit-GEMM MFMA + bias + GN stats.
// v3: 2-row ti ring buffer (kk ordered by ky needs only rows ky,ky+1; row
// ky-1 slot is restaged at kk=3/6 inside the existing barrier pair). LDS
// 78.3KB -> 50.5KB => 3 blocks/CU (12 waves) instead of 2. Barrier count
// unchanged (18). MFMA math / fragment layout / epilogue identical.
// ---------------------------------------------------------------------------
template<int FP32>
__global__ __launch_bounds__(256, 3)
void conv3x3_mfma_kernel(const void* __restrict__ xin,
                         const ushort_t* __restrict__ wbf,   // [9][96][96] bf16
                         const float* __restrict__ bias,
                         float* __restrict__ out,
                         float* __restrict__ stats) {
    __shared__ __align__(16) ushort_t ti2[2 * 66 * ICP];   // 27,456 B
    __shared__ __align__(16) ushort_t wc[96 * ICP];        // 19,968 B
    __shared__ float red[4][96][2];                        //  3,072 B

    const int b   = blockIdx.z;
    const int y0  = blockIdx.y * 2;
    const int x0  = blockIdx.x * 64;
    const int tid = threadIdx.x;
    const int wv   = tid >> 6;
    const int lane = tid & 63;
    const int l15  = lane & 15;
    const int quad = lane >> 4;

    // initial: rows y0-1 -> slot0, y0 -> slot1
    stage_row<FP32>(xin, ti2, b, y0 - 1, x0, 0, tid);
    stage_row<FP32>(xin, ti2, b, y0 + 0, x0, 1, tid);

    // ---- per-thread weight-staging task table (loop-invariant offsets)
    int wsrc[5], wdst[5];
#pragma unroll
    for (int i = 0; i < 5; ++i) {
        int idx = tid + i * 256;
        int icb = idx % 12;
        int oc  = idx / 12;
        wsrc[i] = oc * 96 + icb * 8;
        wdst[i] = oc * ICP + icb * 8;
    }
    u16x8 wreg[5];
#pragma unroll
    for (int i = 0; i < 4; ++i) wreg[i] = *(const u16x8*)&wbf[wsrc[i]];
    if (tid < 128) wreg[4] = *(const u16x8*)&wbf[wsrc[4]];

    f32x4 acc[2][6];
#pragma unroll
    for (int m = 0; m < 2; ++m)
#pragma unroll
        for (int nt = 0; nt < 6; ++nt)
            acc[m][nt] = (f32x4){0.f, 0.f, 0.f, 0.f};

#pragma unroll 1
    for (int kk = 0; kk < 9; ++kk) {
        const int ky = (kk >= 6) ? 2 : (kk >= 3 ? 1 : 0);
        const int kx = kk - 3 * ky;
        const int sA = ky & 1;          // slot of input row ky   (output row m=0)
        const int sB = sA ^ 1;          // slot of input row ky+1 (output row m=1)

        __syncthreads();   // prev compute done reading wc + ti slots
#pragma unroll
        for (int i = 0; i < 4; ++i) *(u16x8*)&wc[wdst[i]] = wreg[i];
        if (tid < 128) *(u16x8*)&wc[wdst[4]] = wreg[4];
        if (kk == 3)      stage_row<FP32>(xin, ti2, b, y0 + 1, x0, 0, tid);
        else if (kk == 6) stage_row<FP32>(xin, ti2, b, y0 + 2, x0, 1, tid);
        __syncthreads();
        if (kk < 8) {      // prefetch next kk's weights; completes under MFMA
            const ushort_t* wsk = wbf + (kk + 1) * 9216;
#pragma unroll
            for (int i = 0; i < 4; ++i) wreg[i] = *(const u16x8*)&wsk[wsrc[i]];
            if (tid < 128) wreg[4] = *(const u16x8*)&wsk[wsrc[4]];
        }
#pragma unroll 1
        for (int ck = 0; ck < 3; ++ck) {
            const int kbase = ck * 32 + quad * 8;
            bf16x8 a0 = *(const bf16x8*)&ti2[(sA * 66 + (wv * 16 + l15 + kx)) * ICP + kbase];
            bf16x8 a1 = *(const bf16x8*)&ti2[(sB * 66 + (wv * 16 + l15 + kx)) * ICP + kbase];
#pragma unroll
            for (int nt = 0; nt < 6; ++nt) {
                bf16x8 bv = *(const bf16x8*)&wc[(nt * 16 + l15) * ICP + kbase];
                acc[0][nt] = __builtin_amdgcn_mfma_f32_16x16x32_bf16(a0, bv, acc[0][nt], 0, 0, 0);
                acc[1][nt] = __builtin_amdgcn_mfma_f32_16x16x32_bf16(a1, bv, acc[1][nt], 0, 0, 0);
            }
        }
    }

    float lsum[6], lsq[6];
#pragma unroll
    for (int nt = 0; nt < 6; ++nt) { lsum[nt] = 0.f; lsq[nt] = 0.f; }

#pragma unroll
    for (int m = 0; m < 2; ++m) {
        const int gy = y0 + m;
        const int gx = x0 + wv * 16 + quad * 4;
#pragma unroll
        for (int nt = 0; nt < 6; ++nt) {
            const int oc = nt * 16 + l15;
            const float bz = bias[oc];
            float v0 = acc[m][nt][0] + bz;
            float v1 = acc[m][nt][1] + bz;
            float v2 = acc[m][nt][2] + bz;
            float v3 = acc[m][nt][3] + bz;
            float4 vv = make_float4(v0, v1, v2, v3);
            *(float4*)&out[((size_t)(b * 96 + oc) * H_ + gy) * W_ + gx] = vv;
            lsum[nt] += v0 + v1 + v2 + v3;
            lsq[nt]  += v0 * v0 + v1 * v1 + v2 * v2 + v3 * v3;
        }
    }
#pragma unroll
    for (int nt = 0; nt < 6; ++nt) {
        float s = lsum[nt], q = lsq[nt];
        s += __shfl_down(s, 32, 64);
        s += __shfl_down(s, 16, 64);
        q += __shfl_down(q, 32, 64);
        q += __shfl_down(q, 16, 64);
        if (lane < 16) {
            red[wv][nt * 16 + lane][0] = s;
            red[wv][nt * 16 + lane][1] = q;
        }
    }
    __syncthreads();
    if (tid < 8) {
        const int g = tid >> 1, which = tid & 1;
        float v = 0.f;
        for (int oc = g * CPG_; oc < g * CPG_ + CPG_; ++oc)
            for (int w2 = 0; w2 < 4; ++w2) v += red[w2][oc][which];
        atomicAdd(&stats[(b * 4 + g) * 2 + which], v);
    }
}

// ---------------------------------------------------------------------------
// h = silu(GN(y)) * (1+shift) + bias  (IN-PLACE on d_out), emits stats2
// ---------------------------------------------------------------------------
__global__ void apply1_kernel(const float* y,
                              const float* __restrict__ stats1,
                              const float* __restrict__ g1,
                              const float* __restrict__ be1,
                              const float* __restrict__ tvec,
                              float* h,
                              float* __restrict__ stats2) {
    const int bc = blockIdx.x;
    const int b = bc / C_, c = bc - b * C_;
    const int g = c / CPG_;
    const float sum = stats1[(b * 4 + g) * 2], sumsq = stats1[(b * 4 + g) * 2 + 1];
    const float mean = sum / NPG_;
    const float var  = sumsq / NPG_ - mean * mean;
    const float rstd = rsqrtf(var + 1e-5f);
    const float sc = rstd * g1[c];
    const float sh = be1[c] - mean * sc;
    const float tsc = 1.f + tvec[b * 192 + c];
    const float tbi = tvec[b * 192 + 96 + c];

    const float4* yp = (const float4*)(y + (size_t)bc * HW_);
    float4* hp = (float4*)(h + (size_t)bc * HW_);
    float ls = 0.f, lss = 0.f;
    for (int i = threadIdx.x; i < HW_ / 4; i += 256) {
        float4 v = yp[i];
        float r0 = silu_f(v.x * sc + sh) * tsc + tbi;
        float r1 = silu_f(v.y * sc + sh) * tsc + tbi;
        float r2 = silu_f(v.z * sc + sh) * tsc + tbi;
        float r3 = silu_f(v.w * sc + sh) * tsc + tbi;
        hp[i] = make_float4(r0, r1, r2, r3);
        ls  += r0 + r1 + r2 + r3;
        lss += r0*r0 + r1*r1 + r2*r2 + r3*r3;
    }
    for (int off = 32; off > 0; off >>= 1) {
        ls  += __shfl_down(ls, off, 64);
        lss += __shfl_down(lss, off, 64);
    }
    if ((threadIdx.x & 63) == 0) {
        atomicAdd(&stats2[(b * 4 + g) * 2 + 0], ls);
        atomicAdd(&stats2[(b * 4 + g) * 2 + 1], lss);
    }
}

// ---------------------------------------------------------------------------
// GN apply -> bf16 output (qkv GEMM input)
// ---------------------------------------------------------------------------
__global__ void gn_bf16_kernel(const float* __restrict__ in,
                               const float* __restrict__ stats,
                               const float* __restrict__ gamma,
                               const float* __restrict__ beta,
                               ushort_t* __restrict__ outb) {
    const int bc = blockIdx.x;
    const int b = bc / C_, c = bc - b * C_;
    const int g = c / CPG_;
    const float sum = stats[(b * 4 + g) * 2], sumsq = stats[(b * 4 + g) * 2 + 1];
    const float mean = sum / NPG_;
    const float var  = sumsq / NPG_ - mean * mean;
    const float rstd = rsqrtf(var + 1e-5f);
    const float sc = rstd * gamma[c];
    const float sh = beta[c] - mean * sc;
    const float4* ip = (const float4*)(in + (size_t)bc * HW_);
    ushort4* op = (ushort4*)(outb + (size_t)bc * HW_);
    for (int i = threadIdx.x; i < HW_ / 4; i += 256) {
        float4 v = ip[i];
        ushort4 u = { f2bf(v.x * sc + sh), f2bf(v.y * sc + sh),
                      f2bf(v.z * sc + sh), f2bf(v.w * sc + sh) };
        op[i] = u;
    }
}

// ---------------------------------------------------------------------------
// GN apply fp32 (+silu), in-place capable
// ---------------------------------------------------------------------------
__global__ void gn_apply_kernel(const float* in,
                                const float* __restrict__ stats,
                                const float* __restrict__ gamma,
                                const float* __restrict__ beta,
                                float* out, int dosilu) {
    const int bc = blockIdx.x;
    const int b = bc / C_, c = bc - b * C_;
    const int g = c / CPG_;
    const float sum = stats[(b * 4 + g) * 2], sumsq = stats[(b * 4 + g) * 2 + 1];
    const float mean = sum / NPG_;
    const float var  = sumsq / NPG_ - mean * mean;
    const float rstd = rsqrtf(var + 1e-5f);
    const float sc = rstd * gamma[c];
    const float sh = beta[c] - mean * sc;
    const float4* ip = (const float4*)(in + (size_t)bc * HW_);
    float4* op = (float4*)(out + (size_t)bc * HW_);
    for (int i = threadIdx.x; i < HW_ / 4; i += 256) {
        float4 v = ip[i];
        float r0 = v.x * sc + sh, r1 = v.y * sc + sh;
        float r2 = v.z * sc + sh, r3 = v.w * sc + sh;
        if (dosilu) { r0 = silu_f(r0); r1 = silu_f(r1); r2 = silu_f(r2); r3 = silu_f(r3); }
        op[i] = make_float4(r0, r1, r2, r3);
    }
}

// ---------------------------------------------------------------------------
// qkv 1x1 GEMM (verified; unchanged)
// ---------------------------------------------------------------------------
__global__ __launch_bounds__(256, 3)
void qkv_gemm_kernel(const ushort_t* __restrict__ xq,
                     const float* __restrict__ qw,   // [288][96]
                     const float* __restrict__ qb,
                     ushort_t* __restrict__ qkvbuf) {
    __shared__ __align__(16) ushort_t ti[2 * 64 * ICP];
    __shared__ __align__(16) ushort_t wc[96 * ICP];

    const int bz = blockIdx.z;
    const int b = bz / 3, s = bz - b * 3;
    const int y0 = blockIdx.y * 2;
    const int x0 = blockIdx.x * 64;
    const int tid = threadIdx.x;
    const int wv = tid >> 6, lane = tid & 63;
    const int l15 = lane & 15, quad = lane >> 4;

#pragma unroll
    for (int it = 0; it < 6; ++it) {
        int idx = it * 256 + tid;
        int ic = idx % 96;
        int t2 = idx / 96;
        int xc = t2 & 7;
        int r  = t2 >> 3;
        u16x8 v = *(const u16x8*)&xq[((size_t)(b * 96 + ic) * H_ + y0 + r) * W_ + x0 + xc * 8];
        ushort_t* dst = &ti[(r * 64 + xc * 8) * ICP + ic];
#pragma unroll
        for (int j = 0; j < 8; ++j) dst[j * ICP] = v[j];
    }
#pragma unroll
    for (int it = 0; it < 9; ++it) {
        int idx = it * 256 + tid;
        int icq = idx % 24;
        int oc  = idx / 24;
        float4 wv4 = *(const float4*)&qw[(s * 96 + oc) * 96 + icq * 4];
        ushort4 u = { f2bf(wv4.x), f2bf(wv4.y), f2bf(wv4.z), f2bf(wv4.w) };
        *(ushort4*)&wc[oc * ICP + icq * 4] = u;
    }
    __syncthreads();

    f32x4 acc[2][6];
#pragma unroll
    for (int m = 0; m < 2; ++m)
#pragma unroll
        for (int nt = 0; nt < 6; ++nt) acc[m][nt] = (f32x4){0.f, 0.f, 0.f, 0.f};

#pragma unroll
    for (int ck = 0; ck < 3; ++ck) {
        const int kbase = ck * 32 + quad * 8;
        bf16x8 a0 = *(const bf16x8*)&ti[(0 * 64 + wv * 16 + l15) * ICP + kbase];
        bf16x8 a1 = *(const bf16x8*)&ti[(1 * 64 + wv * 16 + l15) * ICP + kbase];
#pragma unroll
        for (int nt = 0; nt < 6; ++nt) {
            bf16x8 bv = *(const bf16x8*)&wc[(nt * 16 + l15) * ICP + kbase];
            acc[0][nt] = __builtin_amdgcn_mfma_f32_16x16x32_bf16(a0, bv, acc[0][nt], 0, 0, 0);
            acc[1][nt] = __builtin_amdgcn_mfma_f32_16x16x32_bf16(a1, bv, acc[1][nt], 0, 0, 0);
        }
    }

#pragma unroll
    for (int m = 0; m < 2; ++m) {
        const int gy = y0 + m;
        const int gx = x0 + wv * 16 + quad * 4;
#pragma unroll
        for (int nt = 0; nt < 6; ++nt) {
            const int ocg = s * 96 + nt * 16 + l15;
            const float bz2 = qb[ocg];
            ushort4 u = { f2bf(acc[m][nt][0] + bz2), f2bf(acc[m][nt][1] + bz2),
                          f2bf(acc[m][nt][2] + bz2), f2bf(acc[m][nt][3] + bz2) };
            *(ushort4*)&qkvbuf[((size_t)(b * 288 + ocg) * H_ + gy) * W_ + gx] = u;
        }
    }
}

// ---------------------------------------------------------------------------
// Attention v3 (verified in R2; unchanged)
// ---------------------------------------------------------------------------
#define QKC 1288   // qk channel stride (elems)
#define QKR 160    // qk row stride (elems)
#define OSTS 1032  // ost/vrow channel stride (elems)
#define VTS 520    // vt per-window stride (elems)
__global__ __launch_bounds__(256, 2)
void attn2_kernel(const ushort_t* __restrict__ qkv,
                  ushort_t* __restrict__ obuf, int shift, int accumulate) {
    __shared__ __align__(16) ushort_t qk[12 * QKC];        // Q d=0..5, K d=6..11
    __shared__ __align__(16) ushort_t vt[16 * VTS + 32];   // [wx][px][8] slots
    __shared__ __align__(16) ushort_t ost[6 * OSTS];       // V rows, then O staging

    const int h = blockIdx.x, wy = blockIdx.y, b = blockIdx.z;
    const int tid = threadIdx.x;
    const int wv = tid >> 6, lane = tid & 63;
    const int l15 = lane & 15, quad = lane >> 4;

    for (int idx = tid; idx < 2304; idx += 256) {
        int xc = idx & 15;
        int t2 = idx >> 4;
        int r  = t2 & 7;
        int ch = t2 >> 3;                 // 0..17
        int part = ch / 6, d = ch - part * 6;
        int gch = part * 96 + h * 6 + d;  // q / k / v plane
        int gy = (wy * 8 + r + shift) & 127;
        size_t rowb = ((size_t)(b * 288 + gch) * H_ + gy) * W_;
        ushort4 u0, u1;
        if (shift == 0) {
            u0 = *(const ushort4*)&qkv[rowb + xc * 8];
            u1 = *(const ushort4*)&qkv[rowb + xc * 8 + 4];
        } else {
            u0 = *(const ushort4*)&qkv[rowb + ((xc * 8 + 4) & 127)];
            u1 = *(const ushort4*)&qkv[rowb + ((xc * 8 + 8) & 127)];
        }
        ushort_t* dst = (part < 2) ? &qk[ch * QKC + r * QKR + xc * 8]
                                   : &ost[d * OSTS + r * 128 + xc * 8];
        *(ushort4*)dst = u0;
        *(ushort4*)(dst + 4) = u1;
    }
    __syncthreads();

    // transpose V: ost[d][r*128+x] -> vt[wx][r*8+(x&7)][d], zero slots 6,7.
    {
        const int r   = tid >> 5;        // 0..7
        const int pxq = tid & 31;        // 0..31
        const int px  = pxq * 4;
        u16x4 vv[6];
#pragma unroll
        for (int c = 0; c < 6; ++c)
            vv[c] = *(const u16x4*)&ost[c * OSTS + r * 128 + px];
        const int wx = px >> 3;
        const int p7 = px & 7;           // 0 or 4
#pragma unroll
        for (int j = 0; j < 4; ++j) {
            u16x8 t;
            t[0] = vv[0][j]; t[1] = vv[1][j]; t[2] = vv[2][j];
            t[3] = vv[3][j]; t[4] = vv[4][j]; t[5] = vv[5][j];
            t[6] = 0; t[7] = 0;
            *(u16x8*)&vt[wx * VTS + (r * 8 + p7 + j) * 8] = t;
        }
        if (tid < 16) ((unsigned int*)(vt + 16 * VTS))[tid] = 0u;  // tail pad
    }
    __syncthreads();

    const float scale = 0.40824829046386302f;  // 6^-0.5
    const int dcl = (l15 < 6) ? l15 : 5;       // clamp garbage lanes in-bounds
    const int chA = 6 + dcl;                   // K row e
    const int chB = dcl;                       // Q row d

    for (int i = 0; i < 4; ++i) {
        const int wx = wv * 4 + i;
        f32x4 sa = (f32x4){0.f, 0.f, 0.f, 0.f};
#pragma unroll
        for (int ck = 0; ck < 2; ++ck) {
            const int r = ck * 4 + quad;
            bf16x8 af  = *(const bf16x8*)&qk[chA * QKC + r * QKR + wx * 8];
            bf16x8 bfv = *(const bf16x8*)&qk[chB * QKC + r * QKR + wx * 8];
            sa = __builtin_amdgcn_mfma_f32_16x16x32_bf16(af, bfv, sa, 0, 0, 0);
        }
        float s0 = sa[0] * scale, s1 = sa[1] * scale, s2 = sa[2] * scale, s3 = sa[3] * scale;
        float m = -3.4e38f;
        if (quad == 0) m = fmaxf(fmaxf(s0, s1), fmaxf(s2, s3));
        else if (quad == 1) m = fmaxf(s0, s1);
        m = fmaxf(m, __shfl_xor(m, 16, 64));
        m = fmaxf(m, __shfl_xor(m, 32, 64));
        float p0 = (quad <= 1) ? __expf(s0 - m) : 0.f;
        float p1 = (quad <= 1) ? __expf(s1 - m) : 0.f;
        float p2 = (quad == 0) ? __expf(s2 - m) : 0.f;
        float p3 = (quad == 0) ? __expf(s3 - m) : 0.f;
        float sum = p0 + p1 + p2 + p3;
        sum += __shfl_xor(sum, 16, 64);
        sum += __shfl_xor(sum, 32, 64);
        float inv = 1.f / sum;
        p0 *= inv; p1 *= inv; p2 *= inv; p3 *= inv;
        float e4 = __shfl_xor(p0, 16, 64);
        float e5 = __shfl_xor(p1, 16, 64);
        bf16x8 pf;
        pf[0] = (__bf16)p0; pf[1] = (__bf16)p1; pf[2] = (__bf16)p2; pf[3] = (__bf16)p3;
        pf[4] = (__bf16)e4; pf[5] = (__bf16)e5;
        pf[6] = (__bf16)0.f; pf[7] = (__bf16)0.f;
        if (quad != 0) { bf16x8 z = {}; pf = z; }
#pragma unroll
        for (int mt = 0; mt < 4; ++mt) {
            bf16x8 av = *(const bf16x8*)&vt[wx * VTS + (mt * 16 + l15) * 8 + quad * 8];
            f32x4 o = __builtin_amdgcn_mfma_f32_16x16x32_bf16(av, pf, (f32x4){0.f,0.f,0.f,0.f}, 0, 0, 0);
            if (l15 < 6) {
                const int px = mt * 16 + quad * 4;
                const int r = px >> 3, c = px & 7;
                ushort4 st = { f2bf(o[0]), f2bf(o[1]), f2bf(o[2]), f2bf(o[3]) };
                *(ushort4*)&ost[l15 * OSTS + r * 128 + wx * 8 + c] = st;
            }
        }
    }
    __syncthreads();

    for (int idx = tid; idx < 768; idx += 256) {
        int xc = idx & 15;
        int t2 = idx >> 4;
        int r = t2 & 7, d = t2 >> 3;
        int gy = (wy * 8 + r + shift) & 127;
        size_t rowb = ((size_t)(b * 96 + h * 6 + d) * H_ + gy) * W_;
        size_t a0, a1;
        if (shift == 0) { a0 = rowb + xc * 8; a1 = rowb + xc * 8 + 4; }
        else { a0 = rowb + ((xc * 8 + 4) & 127); a1 = rowb + ((xc * 8 + 8) & 127); }
        const ushort_t* src = &ost[d * OSTS + r * 128 + xc * 8];
        ushort4 v0 = *(const ushort4*)src;
        ushort4 v1 = *(const ushort4*)(src + 4);
        if (accumulate) {
            ushort4 q0 = *(const ushort4*)&obuf[a0];
            ushort4 q1 = *(const ushort4*)&obuf[a1];
            v0.x = f2bf(0.5f * (bf2f(v0.x) + bf2f(q0.x)));
            v0.y = f2bf(0.5f * (bf2f(v0.y) + bf2f(q0.y)));
            v0.z = f2bf(0.5f * (bf2f(v0.z) + bf2f(q0.z)));
            v0.w = f2bf(0.5f * (bf2f(v0.w) + bf2f(q0.w)));
            v1.x = f2bf(0.5f * (bf2f(v1.x) + bf2f(q1.x)));
            v1.y = f2bf(0.5f * (bf2f(v1.y) + bf2f(q1.y)));
            v1.z = f2bf(0.5f * (bf2f(v1.z) + bf2f(q1.z)));
            v1.w = f2bf(0.5f * (bf2f(v1.w) + bf2f(q1.w)));
        }
        *(ushort4*)&obuf[a0] = v0;
        *(ushort4*)&obuf[a1] = v1;
    }
}

// ---------------------------------------------------------------------------
// proj 1x1 GEMM + residual add (verified; unchanged)
// ---------------------------------------------------------------------------
__global__ __launch_bounds__(256, 3)
void proj_gemm_kernel(const ushort_t* __restrict__ ob,
                      const float* __restrict__ pw,   // [96][96]
                      const float* __restrict__ pb,
                      const float* __restrict__ resid,
                      ushort_t* __restrict__ h2) {
    __shared__ __align__(16) ushort_t ti[2 * 64 * ICP];
    __shared__ __align__(16) ushort_t wc[96 * ICP];

    const int b = blockIdx.z;
    const int y0 = blockIdx.y * 2;
    const int x0 = blockIdx.x * 64;
    const int tid = threadIdx.x;
    const int wv = tid >> 6, lane = tid & 63;
    const int l15 = lane & 15, quad = lane >> 4;

#pragma unroll
    for (int it = 0; it < 6; ++it) {
        int idx = it * 256 + tid;
        int ic = idx % 96;
        int t2 = idx / 96;
        int xc = t2 & 7;
        int r  = t2 >> 3;
        u16x8 v = *(const u16x8*)&ob[((size_t)(b * 96 + ic) * H_ + y0 + r) * W_ + x0 + xc * 8];
        ushort_t* dst = &ti[(r * 64 + xc * 8) * ICP + ic];
#pragma unroll
        for (int j = 0; j < 8; ++j) dst[j * ICP] = v[j];
    }
#pragma unroll
    for (int it = 0; it < 9; ++it) {
        int idx = it * 256 + tid;
        int icq = idx % 24;
        int oc  = idx / 24;
        float4 wv4 = *(const float4*)&pw[oc * 96 + icq * 4];
        ushort4 u = { f2bf(wv4.x), f2bf(wv4.y), f2bf(wv4.z), f2bf(wv4.w) };
        *(ushort4*)&wc[oc * ICP + icq * 4] = u;
    }
    __syncthreads();

    f32x4 acc[2][6];
#pragma unroll
    for (int m = 0; m < 2; ++m)
#pragma unroll
        for (int nt = 0; nt < 6; ++nt) acc[m][nt] = (f32x4){0.f, 0.f, 0.f, 0.f};

#pragma unroll
    for (int ck = 0; ck < 3; ++ck) {
        const int kbase = ck * 32 + quad * 8;
        bf16x8 a0 = *(const bf16x8*)&ti[(0 * 64 + wv * 16 + l15) * ICP + kbase];
        bf16x8 a1 = *(const bf16x8*)&ti[(1 * 64 + wv * 16 + l15) * ICP + kbase];
#pragma unroll
        for (int nt = 0; nt < 6; ++nt) {
            bf16x8 bv = *(const bf16x8*)&wc[(nt * 16 + l15) * ICP + kbase];
            acc[0][nt] = __builtin_amdgcn_mfma_f32_16x16x32_bf16(a0, bv, acc[0][nt], 0, 0, 0);
            acc[1][nt] = __builtin_amdgcn_mfma_f32_16x16x32_bf16(a1, bv, acc[1][nt], 0, 0, 0);
        }
    }

#pragma unroll
    for (int m = 0; m < 2; ++m) {
        const int gy = y0 + m;
        const int gx = x0 + wv * 16 + quad * 4;
#pragma unroll
        for (int nt = 0; nt < 6; ++nt) {
            const int oc = nt * 16 + l15;
            const float bz2 = pb[oc];
            size_t addr = ((size_t)(b * 96 + oc) * H_ + gy) * W_ + gx;
            float4 rv = *(const float4*)&resid[addr];
            ushort4 u = { f2bf(acc[m][nt][0] + bz2 + rv.x),
                          f2bf(acc[m][nt][1] + bz2 + rv.y),
                          f2bf(acc[m][nt][2] + bz2 + rv.z),
                          f2bf(acc[m][nt][3] + bz2 + rv.w) };
            *(ushort4*)&h2[addr] = u;
        }
    }
}

// ---------------------------------------------------------------------------
extern "C" void kernel_launch(void* const* d_in, const int* in_sizes, int n_in,
                              void* d_out, int out_size, void* d_ws, size_t ws_size,
                              hipStream_t stream) {
    const float* x     = (const float*)d_in[0];
    const float* t_emb = (const float*)d_in[1];
    const float* w1    = (const float*)d_in[2];
    const float* b1    = (const float*)d_in[3];
    const float* g1    = (const float*)d_in[4];
    const float* be1   = (const float*)d_in[5];
    const float* wt    = (const float*)d_in[6];
    const float* bt    = (const float*)d_in[7];
    const float* qkv_w = (const float*)d_in[8];
    const float* qkv_b = (const float*)d_in[9];
    const float* proj_w= (const float*)d_in[10];
    const float* proj_b= (const float*)d_in[11];
    const float* ga    = (const float*)d_in[12];
    const float* ba    = (const float*)d_in[13];
    const float* w2    = (const float*)d_in[14];
    const float* b2    = (const float*)d_in[15];
    const float* g2    = (const float*)d_in[16];
    const float* be2   = (const float*)d_in[17];

    float* out = (float*)d_out;

    // Workspace arena:
    // A: PLANE bf16  — xq -> Obuf
    // B: 3*PLANE bf16 — qkvbuf -> h2 (first PLANE)
    // tail: stats(384f) + tvec(3072f) + wbf1/wbf2 (2 x 82944 bf16)
    ushort_t* A  = (ushort_t*)d_ws;
    ushort_t* Bq = A + PLANE_;
    float* stats = (float*)(Bq + 3 * PLANE_);   // 384 floats
    float* tvec  = stats + 384;                 // 3072 floats
    ushort_t* wbf1 = (ushort_t*)(tvec + 3072);  // [9][96][96] bf16
    ushort_t* wbf2 = wbf1 + 82944;

    hipMemsetAsync(stats, 0, 384 * sizeof(float), stream);
    temb_kernel<<<12, 256, 0, stream>>>(t_emb, wt, bt, tvec);
    castw_kernel<<<324, 256, 0, stream>>>(w1, w2, wbf1, wbf2);

    // conv1: x (fp32, cast fused into staging) -> y1 (d_out), stats1
    conv3x3_mfma_kernel<1><<<dim3(2, 64, 16), 256, 0, stream>>>((const void*)x, wbf1, b1, out, stats);

    // h = silu(GN(y1))*(1+shift)+bias, in-place on d_out; stats2
    apply1_kernel<<<B_ * C_, 256, 0, stream>>>(out, stats, g1, be1, tvec, out, stats + 128);
    // xq = bf16(GN(h; ga, ba)) -> A
    gn_bf16_kernel<<<B_ * C_, 256, 0, stream>>>(out, stats + 128, ga, ba, A);

    // qkv = conv1x1(xq) -> Bq (288 bf16 planes per batch)
    qkv_gemm_kernel<<<dim3(2, 64, 48), 256, 0, stream>>>(A, qkv_w, qkv_b, Bq);

    // attention: O0 -> A; then A = 0.5*(O0 + O4)
    attn2_kernel<<<dim3(16, 16, 16), 256, 0, stream>>>(Bq, A, 0, 0);
    attn2_kernel<<<dim3(16, 16, 16), 256, 0, stream>>>(Bq, A, 4, 1);

    // h2 = h + proj(A) + pb -> Bq (bf16)
    proj_gemm_kernel<<<dim3(2, 64, 16), 256, 0, stream>>>(A, proj_w, proj_b, out, Bq);

    // conv2: h2 (bf16) -> y2 (d_out), stats3
    conv3x3_mfma_kernel<0><<<dim3(2, 64, 16), 256, 0, stream>>>((const void*)Bq, wbf2, b2, out, stats + 256);

    // out = silu(GN(y2)), in-place
    gn_apply_kernel<<<B_ * C_, 256, 0, stream>>>(out, stats + 256, g2, be2, out, 1);
}